// Round 5
// baseline (928.621 us; speedup 1.0000x reference)
//
#include <hip/hip_runtime.h>
#include <hip/hip_bf16.h>

#pragma clang fp contract(off)

typedef unsigned short u16;
typedef __attribute__((ext_vector_type(4))) float f32x4;
typedef __attribute__((ext_vector_type(4))) unsigned short u16x4;

__device__ __forceinline__ float bf2f(u16 u) {
    union { unsigned int i; float f; } v; v.i = ((unsigned int)u) << 16; return v.f;
}
__device__ __forceinline__ u16 f2bf(float f) {
    __hip_bfloat16 h = __float2bfloat16(f);  // RNE
    return *(u16*)&h;
}

// ---------------------------------------------------------------------------
// Prep: build packed per-position records from channel-major f32 e,g tables.
// Record (RECB bytes): [ECH x bf16 e | ECH x f32 g].  LDS-tiled transpose,
// coalesced loads; writes: lanes cover consecutive c within a pos.
// ---------------------------------------------------------------------------
template<int CC, int TP, int ECH, int RECB>
__global__ __launch_bounds__(256) void prep_records(
    const float* __restrict__ e, const float* __restrict__ g,
    char* __restrict__ dst, int HW)
{
    __shared__ float tile[CC][TP + 1];
    const int tbase = blockIdx.x * TP;
    const int t = threadIdx.x;
    constexpr int ITER = CC * TP / 256;
#pragma unroll
    for (int i = 0; i < ITER; ++i) {
        int eidx = i * 256 + t;
        int c  = eidx / TP;
        int pl = eidx % TP;
        const float* src = (c < CC / 2) ? e : g;
        int cs = (c < CC / 2) ? c : (c - CC / 2);
        tile[c][pl] = src[(size_t)cs * HW + tbase + pl];
    }
    __syncthreads();
#pragma unroll
    for (int i = 0; i < ITER; ++i) {
        int eidx = i * 256 + t;
        int pl = eidx / CC;
        int c  = eidx % CC;
        char* rec = dst + (size_t)(tbase + pl) * RECB;
        if (c < ECH)
            *(u16*)(rec + c * 2) = f2bf(tile[c][pl]);
        else
            *(float*)(rec + ECH * 2 + (c - ECH) * 4) = tile[c][pl];
    }
}

// ---------------------------------------------------------------------------
// Plane sampler on packed records (192 B = 32 bf16 e | 32 f32 g).
// g interpolation in the reference's exact f32 order (gate is sign-critical).
// ---------------------------------------------------------------------------
__device__ __forceinline__ float sample_plane_packed(
    const char* __restrict__ tp, float gx, float gy)
{
    float ix = fminf(fmaxf((gx + 1.0f) * 0.5f * 127.0f, 0.0f), 127.0f);
    float iy = fminf(fmaxf((gy + 1.0f) * 0.5f * 127.0f, 0.0f), 127.0f);
    float x0f = floorf(ix), y0f = floorf(iy);
    float wx = ix - x0f, wy = iy - y0f;
    int x0 = (int)x0f, y0 = (int)y0f;
    int x1 = x0 + 1, y1 = y0 + 1;
    float vx1 = (x1 < 128) ? 1.0f : 0.0f;
    float vy1 = (y1 < 128) ? 1.0f : 0.0f;
    int x1c = min(x1, 127), y1c = min(y1, 127);
    float omwx = 1.0f - wx, omwy = 1.0f - wy;
    float w00 = omwx * omwy;
    float w10 = (wx * omwy) * vx1;
    float w01 = (omwx * wy) * vy1;
    float w11 = ((wx * wy) * vx1) * vy1;
    unsigned o00 = (unsigned)(y0  * 128 + x0 ) * 192u;
    unsigned o10 = (unsigned)(y0  * 128 + x1c) * 192u;
    unsigned o01 = (unsigned)(y1c * 128 + x0 ) * 192u;
    unsigned o11 = (unsigned)(y1c * 128 + x1c) * 192u;
    const char* b00 = tp + o00;
    const char* b10 = tp + o10;
    const char* b01 = tp + o01;
    const char* b11 = tp + o11;
    float acc = 0.0f;
#pragma unroll
    for (int cc = 0; cc < 32; cc += 4) {
        u16x4 ea = *(const u16x4*)(b00 + cc * 2);
        u16x4 eb = *(const u16x4*)(b10 + cc * 2);
        u16x4 ecv = *(const u16x4*)(b01 + cc * 2);
        u16x4 ed = *(const u16x4*)(b11 + cc * 2);
        f32x4 ga = *(const f32x4*)(b00 + 64 + cc * 4);
        f32x4 gb = *(const f32x4*)(b10 + 64 + cc * 4);
        f32x4 gc = *(const f32x4*)(b01 + 64 + cc * 4);
        f32x4 gd = *(const f32x4*)(b11 + 64 + cc * 4);
#pragma unroll
        for (int j = 0; j < 4; ++j) {
            float ei = ((bf2f(ea[j]) * w00 + bf2f(eb[j]) * w10)
                        + bf2f(ecv[j]) * w01) + bf2f(ed[j]) * w11;
            float gi = ((ga[j] * w00 + gb[j] * w10) + gc[j] * w01) + gd[j] * w11;
            acc += (gi >= 0.0f) ? ei : 0.0f;
        }
    }
    return acc;
}

// ---------------------------------------------------------------------------
// Volume sampler on packed records (96 B = 16 bf16 e | 16 f32 g).
// Reference tt order (dz major), w = (fx*fy)*fz, f32 accumulation for g.
// ---------------------------------------------------------------------------
__device__ __forceinline__ float sample_volume_packed(
    const char* __restrict__ tv, float gx, float gy, float gz)
{
    float ix = fminf(fmaxf((gx + 1.0f) * 0.5f * 63.0f, 0.0f), 63.0f);
    float iy = fminf(fmaxf((gy + 1.0f) * 0.5f * 63.0f, 0.0f), 63.0f);
    float iz = fminf(fmaxf((gz + 1.0f) * 0.5f * 63.0f, 0.0f), 63.0f);
    float x0f = floorf(ix), y0f = floorf(iy), z0f = floorf(iz);
    float wx = ix - x0f, wy = iy - y0f, wz = iz - z0f;
    int x0 = (int)x0f, y0 = (int)y0f, z0 = (int)z0f;
    int x1 = x0 + 1, y1 = y0 + 1, z1 = z0 + 1;
    float fx[2] = {1.0f - wx, wx}, fy[2] = {1.0f - wy, wy}, fz[2] = {1.0f - wz, wz};
    float vx[2] = {1.0f, (x1 < 64) ? 1.0f : 0.0f};
    float vy[2] = {1.0f, (y1 < 64) ? 1.0f : 0.0f};
    float vz[2] = {1.0f, (z1 < 64) ? 1.0f : 0.0f};
    int xi[2] = {x0, min(x1, 63)}, yi[2] = {y0, min(y1, 63)}, zi[2] = {z0, min(z1, 63)};

    unsigned off[8];
    float w[8];
#pragma unroll
    for (int dz = 0; dz < 2; ++dz)
#pragma unroll
        for (int dy = 0; dy < 2; ++dy)
#pragma unroll
            for (int dx = 0; dx < 2; ++dx) {
                int tt = (dz << 2) | (dy << 1) | dx;   // reference add order
                w[tt] = (((fx[dx] * fy[dy]) * fz[dz]) * vx[dx]) * (vy[dy] * vz[dz]);
                off[tt] = (unsigned)((zi[dz] * 64 + yi[dy]) * 64 + xi[dx]) * 96u;
            }
    float acc = 0.0f;
#pragma unroll
    for (int cc = 0; cc < 16; cc += 4) {
        f32x4 eacc = {0.0f, 0.0f, 0.0f, 0.0f};
        f32x4 gacc = {0.0f, 0.0f, 0.0f, 0.0f};
#pragma unroll
        for (int tt = 0; tt < 8; ++tt) {
            const char* bp = tv + off[tt];
            u16x4 ev = *(const u16x4*)(bp + cc * 2);
            f32x4 gv = *(const f32x4*)(bp + 32 + cc * 4);
#pragma unroll
            for (int j = 0; j < 4; ++j) {
                eacc[j] = eacc[j] + bf2f(ev[j]) * w[tt];
                gacc[j] = gacc[j] + gv[j] * w[tt];
            }
        }
#pragma unroll
        for (int j = 0; j < 4; ++j)
            acc += (gacc[j] >= 0.0f) ? eacc[j] : 0.0f;
    }
    return acc;
}

// ---------------------------------------------------------------------------
// Line term: constant across points (W=1 -> ix=0 wx=0; gy=0 -> iy=63.5)
// ---------------------------------------------------------------------------
__device__ __forceinline__ float line_pair(const float* __restrict__ e,
                                           const float* __restrict__ g, int c)
{
    float ev = e[c * 128 + 63] * 0.5f + e[c * 128 + 64] * 0.5f;
    float gv = g[c * 128 + 63] * 0.5f + g[c * 128 + 64] * 0.5f;
    return (gv >= 0.0f) ? ev : 0.0f;
}

__device__ __forceinline__ float block_line_const(
    const float* lx, const float* ly, const float* lz,
    const float* lxg, const float* lyg, const float* lzg)
{
    __shared__ float lc_sh;
    int t = threadIdx.x;
    if (t < 64) {
        float part = line_pair(lx, lxg, t) + line_pair(ly, lyg, t) + line_pair(lz, lzg, t);
#pragma unroll
        for (int off = 32; off > 0; off >>= 1) part += __shfl_down(part, off);
        if (t == 0) lc_sh = part;
    }
    __syncthreads();
    return lc_sh;
}

// ---------------------------------------------------------------------------
// Main kernel (packed records)
// ---------------------------------------------------------------------------
__global__ __launch_bounds__(256, 4) void ctri_main_P(
    const float* __restrict__ coords,
    const float* __restrict__ lx,  const float* __restrict__ ly,  const float* __restrict__ lz,
    const float* __restrict__ lxg, const float* __restrict__ lyg, const float* __restrict__ lzg,
    const char* __restrict__ tpxy, const char* __restrict__ tpyz, const char* __restrict__ tpxz,
    const char* __restrict__ tv,
    float* __restrict__ out, int P)
{
    float lc = block_line_const(lx, ly, lz, lxg, lyg, lzg);
    int p = blockIdx.x * blockDim.x + threadIdx.x;
    if (p >= P) return;
    float x = coords[3 * p + 0];
    float y = coords[3 * p + 1];
    float z = coords[3 * p + 2];
    float acc = lc;
    acc += sample_plane_packed(tpxy, x, y);
    acc += sample_plane_packed(tpyz, y, z);
    acc += sample_plane_packed(tpxz, x, z);
    acc += sample_volume_packed(tv, x, y, z);
    out[p] = acc;
}

// ---------------------------------------------------------------------------
// Direct-layout f32 fallback (used only if ws_size too small)
// ---------------------------------------------------------------------------
__device__ __forceinline__ float sample_plane_pair_D(
    const float* __restrict__ e, const float* __restrict__ g, float gx, float gy)
{
    float ix = fminf(fmaxf((gx + 1.0f) * 0.5f * 127.0f, 0.0f), 127.0f);
    float iy = fminf(fmaxf((gy + 1.0f) * 0.5f * 127.0f, 0.0f), 127.0f);
    float x0f = floorf(ix), y0f = floorf(iy);
    float wx = ix - x0f, wy = iy - y0f;
    int x0 = (int)x0f, y0 = (int)y0f;
    int x1 = x0 + 1, y1 = y0 + 1;
    float vx1 = (x1 < 128) ? 1.0f : 0.0f;
    float vy1 = (y1 < 128) ? 1.0f : 0.0f;
    int x1c = min(x1, 127), y1c = min(y1, 127);
    float omwx = 1.0f - wx, omwy = 1.0f - wy;
    float w00 = omwx * omwy;
    float w10 = (wx * omwy) * vx1;
    float w01 = (omwx * wy) * vy1;
    float w11 = ((wx * wy) * vx1) * vy1;
    int o00 = y0 * 128 + x0, o10 = y0 * 128 + x1c;
    int o01 = y1c * 128 + x0, o11 = y1c * 128 + x1c;
    float acc = 0.0f;
#pragma unroll 4
    for (int c = 0; c < 32; ++c) {
        const float* ec = e + (size_t)c * 16384;
        const float* gc = g + (size_t)c * 16384;
        float ei = ((ec[o00] * w00 + ec[o10] * w10) + ec[o01] * w01) + ec[o11] * w11;
        float gi = ((gc[o00] * w00 + gc[o10] * w10) + gc[o01] * w01) + gc[o11] * w11;
        acc += (gi >= 0.0f) ? ei : 0.0f;
    }
    return acc;
}

__device__ __forceinline__ float sample_volume_D(
    const float* __restrict__ e, const float* __restrict__ g,
    float gx, float gy, float gz)
{
    float ix = fminf(fmaxf((gx + 1.0f) * 0.5f * 63.0f, 0.0f), 63.0f);
    float iy = fminf(fmaxf((gy + 1.0f) * 0.5f * 63.0f, 0.0f), 63.0f);
    float iz = fminf(fmaxf((gz + 1.0f) * 0.5f * 63.0f, 0.0f), 63.0f);
    float x0f = floorf(ix), y0f = floorf(iy), z0f = floorf(iz);
    float wx = ix - x0f, wy = iy - y0f, wz = iz - z0f;
    int x0 = (int)x0f, y0 = (int)y0f, z0 = (int)z0f;
    int x1 = x0 + 1, y1 = y0 + 1, z1 = z0 + 1;
    float fx[2] = {1.0f - wx, wx}, fy[2] = {1.0f - wy, wy}, fz[2] = {1.0f - wz, wz};
    float vx[2] = {1.0f, (x1 < 64) ? 1.0f : 0.0f};
    float vy[2] = {1.0f, (y1 < 64) ? 1.0f : 0.0f};
    float vz[2] = {1.0f, (z1 < 64) ? 1.0f : 0.0f};
    int xi[2] = {x0, min(x1, 63)}, yi[2] = {y0, min(y1, 63)}, zi[2] = {z0, min(z1, 63)};
    int o[8]; float w[8];
#pragma unroll
    for (int dz = 0; dz < 2; ++dz)
#pragma unroll
        for (int dy = 0; dy < 2; ++dy)
#pragma unroll
            for (int dx = 0; dx < 2; ++dx) {
                int tt = (dz << 2) | (dy << 1) | dx;
                w[tt] = (((fx[dx] * fy[dy]) * fz[dz]) * vx[dx]) * (vy[dy] * vz[dz]);
                o[tt] = (zi[dz] * 64 + yi[dy]) * 64 + xi[dx];
            }
    float acc = 0.0f;
#pragma unroll 2
    for (int c = 0; c < 16; ++c) {
        const float* ec = e + (size_t)c * 262144;
        const float* gc = g + (size_t)c * 262144;
        float ei = 0.0f, gi = 0.0f;
#pragma unroll
        for (int tt = 0; tt < 8; ++tt) {
            ei = ei + ec[o[tt]] * w[tt];
            gi = gi + gc[o[tt]] * w[tt];
        }
        acc += (gi >= 0.0f) ? ei : 0.0f;
    }
    return acc;
}

__global__ __launch_bounds__(256) void ctri_main_D(
    const float* __restrict__ coords,
    const float* __restrict__ lx,  const float* __restrict__ ly,  const float* __restrict__ lz,
    const float* __restrict__ lxg, const float* __restrict__ lyg, const float* __restrict__ lzg,
    const float* __restrict__ pxy, const float* __restrict__ pyz, const float* __restrict__ pxz,
    const float* __restrict__ pxyg, const float* __restrict__ pyzg, const float* __restrict__ pxzg,
    const float* __restrict__ vol, const float* __restrict__ volg,
    float* __restrict__ out, int P)
{
    float lc = block_line_const(lx, ly, lz, lxg, lyg, lzg);
    int p = blockIdx.x * blockDim.x + threadIdx.x;
    if (p >= P) return;
    float x = coords[3 * p + 0];
    float y = coords[3 * p + 1];
    float z = coords[3 * p + 2];
    float acc = lc;
    acc += sample_plane_pair_D(pxy, pxyg, x, y);
    acc += sample_plane_pair_D(pyz, pyzg, y, z);
    acc += sample_plane_pair_D(pxz, pxzg, x, z);
    acc += sample_volume_D(vol, volg, x, y, z);
    out[p] = acc;
}

// ---------------------------------------------------------------------------
extern "C" void kernel_launch(void* const* d_in, const int* in_sizes, int n_in,
                              void* d_out, int out_size, void* d_ws, size_t ws_size,
                              hipStream_t stream)
{
    (void)n_in; (void)out_size;
    const float* coords = (const float*)d_in[0];
    const float* pxy  = (const float*)d_in[1];
    const float* pyz  = (const float*)d_in[2];
    const float* pxz  = (const float*)d_in[3];
    const float* pxyg = (const float*)d_in[4];
    const float* pyzg = (const float*)d_in[5];
    const float* pxzg = (const float*)d_in[6];
    const float* lx   = (const float*)d_in[7];
    const float* ly   = (const float*)d_in[8];
    const float* lz   = (const float*)d_in[9];
    const float* lxg  = (const float*)d_in[10];
    const float* lyg  = (const float*)d_in[11];
    const float* lzg  = (const float*)d_in[12];
    const float* vol  = (const float*)d_in[13];
    const float* volg = (const float*)d_in[14];
    float* out = (float*)d_out;

    const int P = in_sizes[0] / 3;                        // 262144
    const size_t planeRec = (size_t)16384 * 192;          // 3 MB each
    const size_t volRec   = (size_t)262144 * 96;          // 24 MB
    const size_t need_bytes = 3 * planeRec + volRec;      // ~34.6 MB

    const int blocks = (P + 255) / 256;
    if (ws_size >= need_bytes) {
        char* tpxy = (char*)d_ws;
        char* tpyz = tpxy + planeRec;
        char* tpxz = tpyz + planeRec;
        char* tv   = tpxz + planeRec;
        // planes: CC=64 (32 e + 32 g), TP=64, ECH=32, RECB=192
        prep_records<64, 64, 32, 192><<<256, 256, 0, stream>>>(pxy, pxyg, tpxy, 16384);
        prep_records<64, 64, 32, 192><<<256, 256, 0, stream>>>(pyz, pyzg, tpyz, 16384);
        prep_records<64, 64, 32, 192><<<256, 256, 0, stream>>>(pxz, pxzg, tpxz, 16384);
        // volume: CC=32 (16 e + 16 g), TP=128, ECH=16, RECB=96
        prep_records<32, 128, 16, 96><<<2048, 256, 0, stream>>>(vol, volg, tv, 262144);
        ctri_main_P<<<blocks, 256, 0, stream>>>(coords, lx, ly, lz, lxg, lyg, lzg,
                                                tpxy, tpyz, tpxz, tv, out, P);
    } else {
        ctri_main_D<<<blocks, 256, 0, stream>>>(coords, lx, ly, lz, lxg, lyg, lzg,
                                                pxy, pyz, pxz, pxyg, pyzg, pxzg,
                                                vol, volg, out, P);
    }
}

// Round 6
// 808.589 us; speedup vs baseline: 1.1484x; 1.1484x over previous
//
#include <hip/hip_runtime.h>
#include <hip/hip_bf16.h>

#pragma clang fp contract(off)

typedef unsigned short u16;
typedef unsigned int u32;
typedef __attribute__((ext_vector_type(4))) float f32x4;
typedef __attribute__((ext_vector_type(8))) unsigned short u16x8;

__device__ __forceinline__ float bf2f(u16 u) {
    union { unsigned int i; float f; } v; v.i = ((unsigned int)u) << 16; return v.f;
}
__device__ __forceinline__ u16 f2bf(float f) {
    __hip_bfloat16 h = __float2bfloat16(f);  // RNE
    return *(u16*)&h;
}

// ---------------------------------------------------------------------------
// Prep: packed per-position records [ECH x bf16 e | ECH x f32 g] (RECB bytes)
// from channel-major f32 e,g tables. LDS-tiled, coalesced loads.
// ---------------------------------------------------------------------------
template<int CC, int TP, int ECH, int RECB>
__global__ __launch_bounds__(256) void prep_records(
    const float* __restrict__ e, const float* __restrict__ g,
    char* __restrict__ dst, int HW)
{
    __shared__ float tile[CC][TP + 1];
    const int tbase = blockIdx.x * TP;
    const int t = threadIdx.x;
    constexpr int ITER = CC * TP / 256;
#pragma unroll
    for (int i = 0; i < ITER; ++i) {
        int eidx = i * 256 + t;
        int c  = eidx / TP;
        int pl = eidx % TP;
        const float* src = (c < CC / 2) ? e : g;
        int cs = (c < CC / 2) ? c : (c - CC / 2);
        tile[c][pl] = src[(size_t)cs * HW + tbase + pl];
    }
    __syncthreads();
#pragma unroll
    for (int i = 0; i < ITER; ++i) {
        int eidx = i * 256 + t;
        int pl = eidx / CC;
        int c  = eidx % CC;
        char* rec = dst + (size_t)(tbase + pl) * RECB;
        if (c < ECH)
            *(u16*)(rec + c * 2) = f2bf(tile[c][pl]);
        else
            *(float*)(rec + ECH * 2 + (c - ECH) * 4) = tile[c][pl];
    }
}

// ---------------------------------------------------------------------------
// Spatial bucketing: 8x8x8 = 512 cells
// ---------------------------------------------------------------------------
__device__ __forceinline__ int cell_of(float x, float y, float z)
{
    int cx = (int)fminf(fmaxf((x + 1.0f) * 4.0f, 0.0f), 7.0f);
    int cy = (int)fminf(fmaxf((y + 1.0f) * 4.0f, 0.0f), 7.0f);
    int cz = (int)fminf(fmaxf((z + 1.0f) * 4.0f, 0.0f), 7.0f);
    return cx + (cy << 3) + (cz << 6);
}

__global__ __launch_bounds__(512) void bucket_zero(u32* __restrict__ gcnt)
{
    gcnt[threadIdx.x] = 0u;
}

__global__ __launch_bounds__(256) void bucket_count(
    const float* __restrict__ coords, u32* __restrict__ gcnt, int P)
{
    __shared__ u32 h[512];
    int t = threadIdx.x;
    h[t] = 0u; h[t + 256] = 0u;
    __syncthreads();
    int p = blockIdx.x * 256 + t;
    if (p < P) {
        float x = coords[3 * p + 0];
        float y = coords[3 * p + 1];
        float z = coords[3 * p + 2];
        atomicAdd(&h[cell_of(x, y, z)], 1u);
    }
    __syncthreads();
    if (h[t])       atomicAdd(&gcnt[t],       h[t]);
    if (h[t + 256]) atomicAdd(&gcnt[t + 256], h[t + 256]);
}

__global__ __launch_bounds__(512) void bucket_scan(
    const u32* __restrict__ gcnt, u32* __restrict__ run)
{
    __shared__ u32 s[512];
    int t = threadIdx.x;
    u32 mine = gcnt[t];
    s[t] = mine;
    __syncthreads();
#pragma unroll
    for (int off = 1; off < 512; off <<= 1) {
        u32 v = (t >= off) ? s[t - off] : 0u;
        __syncthreads();
        s[t] += v;
        __syncthreads();
    }
    run[t] = s[t] - mine;   // exclusive prefix
}

__global__ __launch_bounds__(256) void bucket_scatter(
    const float* __restrict__ coords, u32* __restrict__ run,
    u32* __restrict__ perm, int P)
{
    int p = blockIdx.x * 256 + threadIdx.x;
    if (p >= P) return;
    float x = coords[3 * p + 0];
    float y = coords[3 * p + 1];
    float z = coords[3 * p + 2];
    u32 pos = atomicAdd(&run[cell_of(x, y, z)], 1u);
    perm[pos] = (u32)p;
}

// ---------------------------------------------------------------------------
// Plane sampler (192 B rec = 32 bf16 e | 32 f32 g), single pass per tap:
// all 12 x 16B loads of a tap issued together; g accumulated sequentially
// over taps 00,10,01,11 == reference association ((a+b)+c)+d per channel.
// ---------------------------------------------------------------------------
__device__ __forceinline__ float sample_plane_sorted(
    const char* __restrict__ tp, float gx, float gy)
{
    float ix = fminf(fmaxf((gx + 1.0f) * 0.5f * 127.0f, 0.0f), 127.0f);
    float iy = fminf(fmaxf((gy + 1.0f) * 0.5f * 127.0f, 0.0f), 127.0f);
    float x0f = floorf(ix), y0f = floorf(iy);
    float wx = ix - x0f, wy = iy - y0f;
    int x0 = (int)x0f, y0 = (int)y0f;
    int x1 = x0 + 1, y1 = y0 + 1;
    float vx1 = (x1 < 128) ? 1.0f : 0.0f;
    float vy1 = (y1 < 128) ? 1.0f : 0.0f;
    int x1c = min(x1, 127), y1c = min(y1, 127);
    float omwx = 1.0f - wx, omwy = 1.0f - wy;
    float ws4[4];
    ws4[0] = omwx * omwy;
    ws4[1] = (wx * omwy) * vx1;
    ws4[2] = (omwx * wy) * vy1;
    ws4[3] = ((wx * wy) * vx1) * vy1;
    unsigned o[4];
    o[0] = (unsigned)(y0  * 128 + x0 ) * 192u;
    o[1] = (unsigned)(y0  * 128 + x1c) * 192u;
    o[2] = (unsigned)(y1c * 128 + x0 ) * 192u;
    o[3] = (unsigned)(y1c * 128 + x1c) * 192u;

    f32x4 ea[8], ga[8];
#pragma unroll
    for (int k = 0; k < 8; ++k) { ea[k] = (f32x4)0.0f; ga[k] = (f32x4)0.0f; }

#pragma unroll
    for (int t = 0; t < 4; ++t) {
        const char* bp = tp + o[t];
        float w = ws4[t];
        u16x8 ev[4];
        f32x4 gv[8];
#pragma unroll
        for (int k = 0; k < 4; ++k) ev[k] = *(const u16x8*)(bp + k * 16);
#pragma unroll
        for (int k = 0; k < 8; ++k) gv[k] = *(const f32x4*)(bp + 64 + k * 16);
#pragma unroll
        for (int k = 0; k < 8; ++k)
#pragma unroll
            for (int j = 0; j < 4; ++j)
                ga[k][j] = ga[k][j] + gv[k][j] * w;
#pragma unroll
        for (int k = 0; k < 4; ++k)
#pragma unroll
            for (int j = 0; j < 8; ++j) {
                int c = k * 8 + j;
                ea[c >> 2][c & 3] = ea[c >> 2][c & 3] + bf2f(ev[k][j]) * w;
            }
    }
    float acc = 0.0f;
#pragma unroll
    for (int c = 0; c < 32; ++c)
        acc += (ga[c >> 2][c & 3] >= 0.0f) ? ea[c >> 2][c & 3] : 0.0f;
    return acc;
}

// ---------------------------------------------------------------------------
// Volume sampler (96 B rec = 16 bf16 e | 16 f32 g), single pass per tap,
// reference tt order (dz major), sequential g accumulation == ref order.
// ---------------------------------------------------------------------------
__device__ __forceinline__ float sample_volume_sorted(
    const char* __restrict__ tv, float gx, float gy, float gz)
{
    float ix = fminf(fmaxf((gx + 1.0f) * 0.5f * 63.0f, 0.0f), 63.0f);
    float iy = fminf(fmaxf((gy + 1.0f) * 0.5f * 63.0f, 0.0f), 63.0f);
    float iz = fminf(fmaxf((gz + 1.0f) * 0.5f * 63.0f, 0.0f), 63.0f);
    float x0f = floorf(ix), y0f = floorf(iy), z0f = floorf(iz);
    float wx = ix - x0f, wy = iy - y0f, wz = iz - z0f;
    int x0 = (int)x0f, y0 = (int)y0f, z0 = (int)z0f;
    int x1 = x0 + 1, y1 = y0 + 1, z1 = z0 + 1;
    float fx[2] = {1.0f - wx, wx}, fy[2] = {1.0f - wy, wy}, fz[2] = {1.0f - wz, wz};
    float vx[2] = {1.0f, (x1 < 64) ? 1.0f : 0.0f};
    float vy[2] = {1.0f, (y1 < 64) ? 1.0f : 0.0f};
    float vz[2] = {1.0f, (z1 < 64) ? 1.0f : 0.0f};
    int xi[2] = {x0, min(x1, 63)}, yi[2] = {y0, min(y1, 63)}, zi[2] = {z0, min(z1, 63)};

    unsigned off[8];
    float w[8];
#pragma unroll
    for (int dz = 0; dz < 2; ++dz)
#pragma unroll
        for (int dy = 0; dy < 2; ++dy)
#pragma unroll
            for (int dx = 0; dx < 2; ++dx) {
                int tt = (dz << 2) | (dy << 1) | dx;   // reference add order
                w[tt] = (((fx[dx] * fy[dy]) * fz[dz]) * vx[dx]) * (vy[dy] * vz[dz]);
                off[tt] = (unsigned)((zi[dz] * 64 + yi[dy]) * 64 + xi[dx]) * 96u;
            }
    f32x4 ea[4], ga[4];
#pragma unroll
    for (int k = 0; k < 4; ++k) { ea[k] = (f32x4)0.0f; ga[k] = (f32x4)0.0f; }

#pragma unroll
    for (int tt = 0; tt < 8; ++tt) {
        const char* bp = tv + off[tt];
        float wt = w[tt];
        u16x8 ev[2];
        f32x4 gv[4];
#pragma unroll
        for (int k = 0; k < 2; ++k) ev[k] = *(const u16x8*)(bp + k * 16);
#pragma unroll
        for (int k = 0; k < 4; ++k) gv[k] = *(const f32x4*)(bp + 32 + k * 16);
#pragma unroll
        for (int k = 0; k < 4; ++k)
#pragma unroll
            for (int j = 0; j < 4; ++j)
                ga[k][j] = ga[k][j] + gv[k][j] * wt;
#pragma unroll
        for (int k = 0; k < 2; ++k)
#pragma unroll
            for (int j = 0; j < 8; ++j) {
                int c = k * 8 + j;
                ea[c >> 2][c & 3] = ea[c >> 2][c & 3] + bf2f(ev[k][j]) * wt;
            }
    }
    float acc = 0.0f;
#pragma unroll
    for (int c = 0; c < 16; ++c)
        acc += (ga[c >> 2][c & 3] >= 0.0f) ? ea[c >> 2][c & 3] : 0.0f;
    return acc;
}

// ---------------------------------------------------------------------------
// Line term: constant across points (W=1 -> ix=0 wx=0; gy=0 -> iy=63.5)
// ---------------------------------------------------------------------------
__device__ __forceinline__ float line_pair(const float* __restrict__ e,
                                           const float* __restrict__ g, int c)
{
    float ev = e[c * 128 + 63] * 0.5f + e[c * 128 + 64] * 0.5f;
    float gv = g[c * 128 + 63] * 0.5f + g[c * 128 + 64] * 0.5f;
    return (gv >= 0.0f) ? ev : 0.0f;
}

__device__ __forceinline__ float block_line_const(
    const float* lx, const float* ly, const float* lz,
    const float* lxg, const float* lyg, const float* lzg)
{
    __shared__ float lc_sh;
    int t = threadIdx.x;
    if (t < 64) {
        float part = line_pair(lx, lxg, t) + line_pair(ly, lyg, t) + line_pair(lz, lzg, t);
#pragma unroll
        for (int off = 32; off > 0; off >>= 1) part += __shfl_down(part, off);
        if (t == 0) lc_sh = part;
    }
    __syncthreads();
    return lc_sh;
}

// ---------------------------------------------------------------------------
// Main kernel: permuted point order (bucketed) + XCD-contiguous swizzle
// ---------------------------------------------------------------------------
__global__ __launch_bounds__(256, 4) void ctri_main_S(
    const float* __restrict__ coords, const u32* __restrict__ perm,
    const float* __restrict__ lx,  const float* __restrict__ ly,  const float* __restrict__ lz,
    const float* __restrict__ lxg, const float* __restrict__ lyg, const float* __restrict__ lzg,
    const char* __restrict__ tpxy, const char* __restrict__ tpyz, const char* __restrict__ tpxz,
    const char* __restrict__ tv,
    float* __restrict__ out, int P, int nblk)
{
    float lc = block_line_const(lx, ly, lz, lxg, lyg, lzg);
    int b = blockIdx.x;
    int cpx = nblk >> 3;                 // nblk multiple of 8
    int swz = (b & 7) * cpx + (b >> 3);  // XCD k <- contiguous perm chunk
    int i = swz * 256 + threadIdx.x;
    if (i >= P) return;
    int p = (int)perm[i];
    float x = coords[3 * p + 0];
    float y = coords[3 * p + 1];
    float z = coords[3 * p + 2];
    float acc = lc;
    acc += sample_plane_sorted(tpxy, x, y);
    acc += sample_plane_sorted(tpyz, y, z);
    acc += sample_plane_sorted(tpxz, x, z);
    acc += sample_volume_sorted(tv, x, y, z);
    out[p] = acc;
}

// ---------------------------------------------------------------------------
// Direct-layout f32 fallback (used only if ws_size too small)
// ---------------------------------------------------------------------------
__device__ __forceinline__ float sample_plane_pair_D(
    const float* __restrict__ e, const float* __restrict__ g, float gx, float gy)
{
    float ix = fminf(fmaxf((gx + 1.0f) * 0.5f * 127.0f, 0.0f), 127.0f);
    float iy = fminf(fmaxf((gy + 1.0f) * 0.5f * 127.0f, 0.0f), 127.0f);
    float x0f = floorf(ix), y0f = floorf(iy);
    float wx = ix - x0f, wy = iy - y0f;
    int x0 = (int)x0f, y0 = (int)y0f;
    int x1 = x0 + 1, y1 = y0 + 1;
    float vx1 = (x1 < 128) ? 1.0f : 0.0f;
    float vy1 = (y1 < 128) ? 1.0f : 0.0f;
    int x1c = min(x1, 127), y1c = min(y1, 127);
    float omwx = 1.0f - wx, omwy = 1.0f - wy;
    float w00 = omwx * omwy;
    float w10 = (wx * omwy) * vx1;
    float w01 = (omwx * wy) * vy1;
    float w11 = ((wx * wy) * vx1) * vy1;
    int o00 = y0 * 128 + x0, o10 = y0 * 128 + x1c;
    int o01 = y1c * 128 + x0, o11 = y1c * 128 + x1c;
    float acc = 0.0f;
#pragma unroll 4
    for (int c = 0; c < 32; ++c) {
        const float* ec = e + (size_t)c * 16384;
        const float* gc = g + (size_t)c * 16384;
        float ei = ((ec[o00] * w00 + ec[o10] * w10) + ec[o01] * w01) + ec[o11] * w11;
        float gi = ((gc[o00] * w00 + gc[o10] * w10) + gc[o01] * w01) + gc[o11] * w11;
        acc += (gi >= 0.0f) ? ei : 0.0f;
    }
    return acc;
}

__device__ __forceinline__ float sample_volume_D(
    const float* __restrict__ e, const float* __restrict__ g,
    float gx, float gy, float gz)
{
    float ix = fminf(fmaxf((gx + 1.0f) * 0.5f * 63.0f, 0.0f), 63.0f);
    float iy = fminf(fmaxf((gy + 1.0f) * 0.5f * 63.0f, 0.0f), 63.0f);
    float iz = fminf(fmaxf((gz + 1.0f) * 0.5f * 63.0f, 0.0f), 63.0f);
    float x0f = floorf(ix), y0f = floorf(iy), z0f = floorf(iz);
    float wx = ix - x0f, wy = iy - y0f, wz = iz - z0f;
    int x0 = (int)x0f, y0 = (int)y0f, z0 = (int)z0f;
    int x1 = x0 + 1, y1 = y0 + 1, z1 = z0 + 1;
    float fx[2] = {1.0f - wx, wx}, fy[2] = {1.0f - wy, wy}, fz[2] = {1.0f - wz, wz};
    float vx[2] = {1.0f, (x1 < 64) ? 1.0f : 0.0f};
    float vy[2] = {1.0f, (y1 < 64) ? 1.0f : 0.0f};
    float vz[2] = {1.0f, (z1 < 64) ? 1.0f : 0.0f};
    int xi[2] = {x0, min(x1, 63)}, yi[2] = {y0, min(y1, 63)}, zi[2] = {z0, min(z1, 63)};
    int o[8]; float w[8];
#pragma unroll
    for (int dz = 0; dz < 2; ++dz)
#pragma unroll
        for (int dy = 0; dy < 2; ++dy)
#pragma unroll
            for (int dx = 0; dx < 2; ++dx) {
                int tt = (dz << 2) | (dy << 1) | dx;
                w[tt] = (((fx[dx] * fy[dy]) * fz[dz]) * vx[dx]) * (vy[dy] * vz[dz]);
                o[tt] = (zi[dz] * 64 + yi[dy]) * 64 + xi[dx];
            }
    float acc = 0.0f;
#pragma unroll 2
    for (int c = 0; c < 16; ++c) {
        const float* ec = e + (size_t)c * 262144;
        const float* gc = g + (size_t)c * 262144;
        float ei = 0.0f, gi = 0.0f;
#pragma unroll
        for (int tt = 0; tt < 8; ++tt) {
            ei = ei + ec[o[tt]] * w[tt];
            gi = gi + gc[o[tt]] * w[tt];
        }
        acc += (gi >= 0.0f) ? ei : 0.0f;
    }
    return acc;
}

__global__ __launch_bounds__(256) void ctri_main_D(
    const float* __restrict__ coords,
    const float* __restrict__ lx,  const float* __restrict__ ly,  const float* __restrict__ lz,
    const float* __restrict__ lxg, const float* __restrict__ lyg, const float* __restrict__ lzg,
    const float* __restrict__ pxy, const float* __restrict__ pyz, const float* __restrict__ pxz,
    const float* __restrict__ pxyg, const float* __restrict__ pyzg, const float* __restrict__ pxzg,
    const float* __restrict__ vol, const float* __restrict__ volg,
    float* __restrict__ out, int P)
{
    float lc = block_line_const(lx, ly, lz, lxg, lyg, lzg);
    int p = blockIdx.x * blockDim.x + threadIdx.x;
    if (p >= P) return;
    float x = coords[3 * p + 0];
    float y = coords[3 * p + 1];
    float z = coords[3 * p + 2];
    float acc = lc;
    acc += sample_plane_pair_D(pxy, pxyg, x, y);
    acc += sample_plane_pair_D(pyz, pyzg, y, z);
    acc += sample_plane_pair_D(pxz, pxzg, x, z);
    acc += sample_volume_D(vol, volg, x, y, z);
    out[p] = acc;
}

// ---------------------------------------------------------------------------
extern "C" void kernel_launch(void* const* d_in, const int* in_sizes, int n_in,
                              void* d_out, int out_size, void* d_ws, size_t ws_size,
                              hipStream_t stream)
{
    (void)n_in; (void)out_size;
    const float* coords = (const float*)d_in[0];
    const float* pxy  = (const float*)d_in[1];
    const float* pyz  = (const float*)d_in[2];
    const float* pxz  = (const float*)d_in[3];
    const float* pxyg = (const float*)d_in[4];
    const float* pyzg = (const float*)d_in[5];
    const float* pxzg = (const float*)d_in[6];
    const float* lx   = (const float*)d_in[7];
    const float* ly   = (const float*)d_in[8];
    const float* lz   = (const float*)d_in[9];
    const float* lxg  = (const float*)d_in[10];
    const float* lyg  = (const float*)d_in[11];
    const float* lzg  = (const float*)d_in[12];
    const float* vol  = (const float*)d_in[13];
    const float* volg = (const float*)d_in[14];
    float* out = (float*)d_out;

    const int P = in_sizes[0] / 3;                        // 262144
    const size_t planeRec = (size_t)16384 * 192;          // 3 MB each
    const size_t volRec   = (size_t)262144 * 96;          // 24 MB
    const size_t tabBytes = 3 * planeRec + volRec;        // ~34.6 MB
    const size_t permBytes = (size_t)P * 4;               // 1 MB
    const size_t binBytes  = 512 * 4;
    const size_t need_bytes = tabBytes + permBytes + 2 * binBytes;

    const int blocks = (P + 255) / 256;                   // 1024
    if (ws_size >= need_bytes) {
        char* tpxy = (char*)d_ws;
        char* tpyz = tpxy + planeRec;
        char* tpxz = tpyz + planeRec;
        char* tv   = tpxz + planeRec;
        u32* perm  = (u32*)(tv + volRec);
        u32* gcnt  = perm + P;
        u32* run   = gcnt + 512;

        prep_records<64, 64, 32, 192><<<256, 256, 0, stream>>>(pxy, pxyg, tpxy, 16384);
        prep_records<64, 64, 32, 192><<<256, 256, 0, stream>>>(pyz, pyzg, tpyz, 16384);
        prep_records<64, 64, 32, 192><<<256, 256, 0, stream>>>(pxz, pxzg, tpxz, 16384);
        prep_records<32, 128, 16, 96><<<2048, 256, 0, stream>>>(vol, volg, tv, 262144);

        bucket_zero<<<1, 512, 0, stream>>>(gcnt);
        bucket_count<<<blocks, 256, 0, stream>>>(coords, gcnt, P);
        bucket_scan<<<1, 512, 0, stream>>>(gcnt, run);
        bucket_scatter<<<blocks, 256, 0, stream>>>(coords, run, perm, P);

        ctri_main_S<<<blocks, 256, 0, stream>>>(coords, perm, lx, ly, lz, lxg, lyg, lzg,
                                                tpxy, tpyz, tpxz, tv, out, P, blocks);
    } else {
        ctri_main_D<<<blocks, 256, 0, stream>>>(coords, lx, ly, lz, lxg, lyg, lzg,
                                                pxy, pyz, pxz, pxyg, pyzg, pxzg,
                                                vol, volg, out, P);
    }
}

// Round 7
// 291.069 us; speedup vs baseline: 3.1904x; 2.7780x over previous
//
#include <hip/hip_runtime.h>
#include <hip/hip_bf16.h>

#pragma clang fp contract(off)

typedef unsigned short u16;
typedef unsigned int u32;
typedef __attribute__((ext_vector_type(4))) float f32x4;
typedef __attribute__((ext_vector_type(8))) unsigned short u16x8;
typedef __attribute__((ext_vector_type(4))) unsigned short u16x4;

__device__ __forceinline__ float bf2f(u16 u) {
    union { unsigned int i; float f; } v; v.i = ((unsigned int)u) << 16; return v.f;
}
__device__ __forceinline__ u16 f2bf(float f) {
    __hip_bfloat16 h = __float2bfloat16(f);  // RNE
    return *(u16*)&h;
}

// ---------------------------------------------------------------------------
// Prep: packed per-position records [ECH x bf16 e | ECH x f32 g] (RECB bytes)
// from channel-major f32 e,g tables. LDS-tiled, coalesced loads.
// ---------------------------------------------------------------------------
template<int CC, int TP, int ECH, int RECB>
__global__ __launch_bounds__(256) void prep_records(
    const float* __restrict__ e, const float* __restrict__ g,
    char* __restrict__ dst, int HW)
{
    __shared__ float tile[CC][TP + 1];
    const int tbase = blockIdx.x * TP;
    const int t = threadIdx.x;
    constexpr int ITER = CC * TP / 256;
#pragma unroll
    for (int i = 0; i < ITER; ++i) {
        int eidx = i * 256 + t;
        int c  = eidx / TP;
        int pl = eidx % TP;
        const float* src = (c < CC / 2) ? e : g;
        int cs = (c < CC / 2) ? c : (c - CC / 2);
        tile[c][pl] = src[(size_t)cs * HW + tbase + pl];
    }
    __syncthreads();
#pragma unroll
    for (int i = 0; i < ITER; ++i) {
        int eidx = i * 256 + t;
        int pl = eidx / CC;
        int c  = eidx % CC;
        char* rec = dst + (size_t)(tbase + pl) * RECB;
        if (c < ECH)
            *(u16*)(rec + c * 2) = f2bf(tile[c][pl]);
        else
            *(float*)(rec + ECH * 2 + (c - ECH) * 4) = tile[c][pl];
    }
}

// ---------------------------------------------------------------------------
// Spatial bucketing: 8x8x8 = 512 cells
// ---------------------------------------------------------------------------
__device__ __forceinline__ int cell_of(float x, float y, float z)
{
    int cx = (int)fminf(fmaxf((x + 1.0f) * 4.0f, 0.0f), 7.0f);
    int cy = (int)fminf(fmaxf((y + 1.0f) * 4.0f, 0.0f), 7.0f);
    int cz = (int)fminf(fmaxf((z + 1.0f) * 4.0f, 0.0f), 7.0f);
    return cx + (cy << 3) + (cz << 6);
}

__global__ __launch_bounds__(512) void bucket_zero(u32* __restrict__ gcnt)
{
    gcnt[threadIdx.x] = 0u;
}

__global__ __launch_bounds__(256) void bucket_count(
    const float* __restrict__ coords, u32* __restrict__ gcnt, int P)
{
    __shared__ u32 h[512];
    int t = threadIdx.x;
    h[t] = 0u; h[t + 256] = 0u;
    __syncthreads();
    int p = blockIdx.x * 256 + t;
    if (p < P) {
        float x = coords[3 * p + 0];
        float y = coords[3 * p + 1];
        float z = coords[3 * p + 2];
        atomicAdd(&h[cell_of(x, y, z)], 1u);
    }
    __syncthreads();
    if (h[t])       atomicAdd(&gcnt[t],       h[t]);
    if (h[t + 256]) atomicAdd(&gcnt[t + 256], h[t + 256]);
}

__global__ __launch_bounds__(512) void bucket_scan(
    const u32* __restrict__ gcnt, u32* __restrict__ run)
{
    __shared__ u32 s[512];
    int t = threadIdx.x;
    u32 mine = gcnt[t];
    s[t] = mine;
    __syncthreads();
#pragma unroll
    for (int off = 1; off < 512; off <<= 1) {
        u32 v = (t >= off) ? s[t - off] : 0u;
        __syncthreads();
        s[t] += v;
        __syncthreads();
    }
    run[t] = s[t] - mine;   // exclusive prefix
}

__global__ __launch_bounds__(256) void bucket_scatter(
    const float* __restrict__ coords, u32* __restrict__ run,
    u32* __restrict__ perm, int P)
{
    int p = blockIdx.x * 256 + threadIdx.x;
    if (p >= P) return;
    float x = coords[3 * p + 0];
    float y = coords[3 * p + 1];
    float z = coords[3 * p + 2];
    u32 pos = atomicAdd(&run[cell_of(x, y, z)], 1u);
    perm[pos] = (u32)p;
}

// ---------------------------------------------------------------------------
// Lane-split plane sampler: lane sub-index s (0..3) owns channels s*8..s*8+7.
// Record 192 B = [32 bf16 e | 32 f32 g]; lane reads e 16B + g 32B per tap —
// the 4 lanes of a point cover the full record as contiguous lines.
// g accumulated sequentially over taps 00,10,01,11 == ref association.
// ---------------------------------------------------------------------------
__device__ __forceinline__ float plane_lane(
    const char* __restrict__ tp, float gx, float gy, int s)
{
    float ix = fminf(fmaxf((gx + 1.0f) * 0.5f * 127.0f, 0.0f), 127.0f);
    float iy = fminf(fmaxf((gy + 1.0f) * 0.5f * 127.0f, 0.0f), 127.0f);
    float x0f = floorf(ix), y0f = floorf(iy);
    float wx = ix - x0f, wy = iy - y0f;
    int x0 = (int)x0f, y0 = (int)y0f;
    int x1 = x0 + 1, y1 = y0 + 1;
    float vx1 = (x1 < 128) ? 1.0f : 0.0f;
    float vy1 = (y1 < 128) ? 1.0f : 0.0f;
    int x1c = min(x1, 127), y1c = min(y1, 127);
    float omwx = 1.0f - wx, omwy = 1.0f - wy;
    float ws4[4];
    ws4[0] = omwx * omwy;
    ws4[1] = (wx * omwy) * vx1;
    ws4[2] = (omwx * wy) * vy1;
    ws4[3] = ((wx * wy) * vx1) * vy1;
    unsigned o[4];
    o[0] = (unsigned)(y0  * 128 + x0 ) * 192u;
    o[1] = (unsigned)(y0  * 128 + x1c) * 192u;
    o[2] = (unsigned)(y1c * 128 + x0 ) * 192u;
    o[3] = (unsigned)(y1c * 128 + x1c) * 192u;

    const int eoff = s * 16;
    const int goff = 64 + s * 32;
    f32x4 ea0 = {0.0f, 0.0f, 0.0f, 0.0f}, ea1 = {0.0f, 0.0f, 0.0f, 0.0f};
    f32x4 ga0 = {0.0f, 0.0f, 0.0f, 0.0f}, ga1 = {0.0f, 0.0f, 0.0f, 0.0f};
#pragma unroll
    for (int t = 0; t < 4; ++t) {
        const char* bp = tp + o[t];
        float w = ws4[t];
        u16x8 ev = *(const u16x8*)(bp + eoff);
        f32x4 g0 = *(const f32x4*)(bp + goff);
        f32x4 g1 = *(const f32x4*)(bp + goff + 16);
#pragma unroll
        for (int j = 0; j < 4; ++j) {
            ga0[j] = ga0[j] + g0[j] * w;
            ga1[j] = ga1[j] + g1[j] * w;
            ea0[j] = ea0[j] + bf2f(ev[j]) * w;
            ea1[j] = ea1[j] + bf2f(ev[j + 4]) * w;
        }
    }
    float acc = 0.0f;
#pragma unroll
    for (int j = 0; j < 4; ++j) {
        acc += (ga0[j] >= 0.0f) ? ea0[j] : 0.0f;
        acc += (ga1[j] >= 0.0f) ? ea1[j] : 0.0f;
    }
    return acc;
}

// ---------------------------------------------------------------------------
// Lane-split volume sampler: lane s owns channels s*4..s*4+3.
// Record 96 B = [16 bf16 e | 16 f32 g]; per tap: e 8B + g 16B per lane.
// Reference tt order (dz major), sequential g accumulation == ref order.
// ---------------------------------------------------------------------------
__device__ __forceinline__ float vol_lane(
    const char* __restrict__ tv, float gx, float gy, float gz, int s)
{
    float ix = fminf(fmaxf((gx + 1.0f) * 0.5f * 63.0f, 0.0f), 63.0f);
    float iy = fminf(fmaxf((gy + 1.0f) * 0.5f * 63.0f, 0.0f), 63.0f);
    float iz = fminf(fmaxf((gz + 1.0f) * 0.5f * 63.0f, 0.0f), 63.0f);
    float x0f = floorf(ix), y0f = floorf(iy), z0f = floorf(iz);
    float wx = ix - x0f, wy = iy - y0f, wz = iz - z0f;
    int x0 = (int)x0f, y0 = (int)y0f, z0 = (int)z0f;
    int x1 = x0 + 1, y1 = y0 + 1, z1 = z0 + 1;
    float fx[2] = {1.0f - wx, wx}, fy[2] = {1.0f - wy, wy}, fz[2] = {1.0f - wz, wz};
    float vx[2] = {1.0f, (x1 < 64) ? 1.0f : 0.0f};
    float vy[2] = {1.0f, (y1 < 64) ? 1.0f : 0.0f};
    float vz[2] = {1.0f, (z1 < 64) ? 1.0f : 0.0f};
    int xi[2] = {x0, min(x1, 63)}, yi[2] = {y0, min(y1, 63)}, zi[2] = {z0, min(z1, 63)};

    unsigned off[8];
    float w[8];
#pragma unroll
    for (int dz = 0; dz < 2; ++dz)
#pragma unroll
        for (int dy = 0; dy < 2; ++dy)
#pragma unroll
            for (int dx = 0; dx < 2; ++dx) {
                int tt = (dz << 2) | (dy << 1) | dx;   // reference add order
                w[tt] = (((fx[dx] * fy[dy]) * fz[dz]) * vx[dx]) * (vy[dy] * vz[dz]);
                off[tt] = (unsigned)((zi[dz] * 64 + yi[dy]) * 64 + xi[dx]) * 96u;
            }
    const int eoff = s * 8;
    const int goff = 32 + s * 16;
    f32x4 ea = {0.0f, 0.0f, 0.0f, 0.0f}, ga = {0.0f, 0.0f, 0.0f, 0.0f};
#pragma unroll
    for (int tt = 0; tt < 8; ++tt) {
        const char* bp = tv + off[tt];
        float wt = w[tt];
        u16x4 ev = *(const u16x4*)(bp + eoff);
        f32x4 gv = *(const f32x4*)(bp + goff);
#pragma unroll
        for (int j = 0; j < 4; ++j) {
            ga[j] = ga[j] + gv[j] * wt;
            ea[j] = ea[j] + bf2f(ev[j]) * wt;
        }
    }
    float acc = 0.0f;
#pragma unroll
    for (int j = 0; j < 4; ++j)
        acc += (ga[j] >= 0.0f) ? ea[j] : 0.0f;
    return acc;
}

// ---------------------------------------------------------------------------
// Line term: constant across points (W=1 -> ix=0 wx=0; gy=0 -> iy=63.5)
// ---------------------------------------------------------------------------
__device__ __forceinline__ float line_pair(const float* __restrict__ e,
                                           const float* __restrict__ g, int c)
{
    float ev = e[c * 128 + 63] * 0.5f + e[c * 128 + 64] * 0.5f;
    float gv = g[c * 128 + 63] * 0.5f + g[c * 128 + 64] * 0.5f;
    return (gv >= 0.0f) ? ev : 0.0f;
}

__device__ __forceinline__ float block_line_const(
    const float* lx, const float* ly, const float* lz,
    const float* lxg, const float* lyg, const float* lzg)
{
    __shared__ float lc_sh;
    int t = threadIdx.x;
    if (t < 64) {
        float part = line_pair(lx, lxg, t) + line_pair(ly, lyg, t) + line_pair(lz, lzg, t);
#pragma unroll
        for (int off = 32; off > 0; off >>= 1) part += __shfl_down(part, off);
        if (t == 0) lc_sh = part;
    }
    __syncthreads();
    return lc_sh;
}

// ---------------------------------------------------------------------------
// Main kernel: 4 lanes per point, bucketed order + XCD-contiguous swizzle.
// No forced occupancy bound — low pressure by construction (no spills).
// ---------------------------------------------------------------------------
__global__ __launch_bounds__(256) void ctri_main_L(
    const float* __restrict__ coords, const u32* __restrict__ perm,
    const float* __restrict__ lx,  const float* __restrict__ ly,  const float* __restrict__ lz,
    const float* __restrict__ lxg, const float* __restrict__ lyg, const float* __restrict__ lzg,
    const char* __restrict__ tpxy, const char* __restrict__ tpyz, const char* __restrict__ tpxz,
    const char* __restrict__ tv,
    float* __restrict__ out, int P, int nblk)
{
    float lc = block_line_const(lx, ly, lz, lxg, lyg, lzg);
    int b = blockIdx.x;
    int cpx = nblk >> 3;                 // nblk multiple of 8
    int swz = (b & 7) * cpx + (b >> 3);  // XCD k <- contiguous perm chunk
    int i = swz * 64 + (threadIdx.x >> 2);
    int s = threadIdx.x & 3;
    if (i >= P) return;
    int p = (int)perm[i];
    float x = coords[3 * p + 0];
    float y = coords[3 * p + 1];
    float z = coords[3 * p + 2];
    float part = 0.0f;
    part += plane_lane(tpxy, x, y, s);
    part += plane_lane(tpyz, y, z, s);
    part += plane_lane(tpxz, x, z, s);
    part += vol_lane(tv, x, y, z, s);
    part += __shfl_xor(part, 1, 64);
    part += __shfl_xor(part, 2, 64);
    if (s == 0) out[p] = lc + part;
}

// ---------------------------------------------------------------------------
// Direct-layout f32 fallback (used only if ws_size too small)
// ---------------------------------------------------------------------------
__device__ __forceinline__ float sample_plane_pair_D(
    const float* __restrict__ e, const float* __restrict__ g, float gx, float gy)
{
    float ix = fminf(fmaxf((gx + 1.0f) * 0.5f * 127.0f, 0.0f), 127.0f);
    float iy = fminf(fmaxf((gy + 1.0f) * 0.5f * 127.0f, 0.0f), 127.0f);
    float x0f = floorf(ix), y0f = floorf(iy);
    float wx = ix - x0f, wy = iy - y0f;
    int x0 = (int)x0f, y0 = (int)y0f;
    int x1 = x0 + 1, y1 = y0 + 1;
    float vx1 = (x1 < 128) ? 1.0f : 0.0f;
    float vy1 = (y1 < 128) ? 1.0f : 0.0f;
    int x1c = min(x1, 127), y1c = min(y1, 127);
    float omwx = 1.0f - wx, omwy = 1.0f - wy;
    float w00 = omwx * omwy;
    float w10 = (wx * omwy) * vx1;
    float w01 = (omwx * wy) * vy1;
    float w11 = ((wx * wy) * vx1) * vy1;
    int o00 = y0 * 128 + x0, o10 = y0 * 128 + x1c;
    int o01 = y1c * 128 + x0, o11 = y1c * 128 + x1c;
    float acc = 0.0f;
#pragma unroll 4
    for (int c = 0; c < 32; ++c) {
        const float* ec = e + (size_t)c * 16384;
        const float* gc = g + (size_t)c * 16384;
        float ei = ((ec[o00] * w00 + ec[o10] * w10) + ec[o01] * w01) + ec[o11] * w11;
        float gi = ((gc[o00] * w00 + gc[o10] * w10) + gc[o01] * w01) + gc[o11] * w11;
        acc += (gi >= 0.0f) ? ei : 0.0f;
    }
    return acc;
}

__device__ __forceinline__ float sample_volume_D(
    const float* __restrict__ e, const float* __restrict__ g,
    float gx, float gy, float gz)
{
    float ix = fminf(fmaxf((gx + 1.0f) * 0.5f * 63.0f, 0.0f), 63.0f);
    float iy = fminf(fmaxf((gy + 1.0f) * 0.5f * 63.0f, 0.0f), 63.0f);
    float iz = fminf(fmaxf((gz + 1.0f) * 0.5f * 63.0f, 0.0f), 63.0f);
    float x0f = floorf(ix), y0f = floorf(iy), z0f = floorf(iz);
    float wx = ix - x0f, wy = iy - y0f, wz = iz - z0f;
    int x0 = (int)x0f, y0 = (int)y0f, z0 = (int)z0f;
    int x1 = x0 + 1, y1 = y0 + 1, z1 = z0 + 1;
    float fx[2] = {1.0f - wx, wx}, fy[2] = {1.0f - wy, wy}, fz[2] = {1.0f - wz, wz};
    float vx[2] = {1.0f, (x1 < 64) ? 1.0f : 0.0f};
    float vy[2] = {1.0f, (y1 < 64) ? 1.0f : 0.0f};
    float vz[2] = {1.0f, (z1 < 64) ? 1.0f : 0.0f};
    int xi[2] = {x0, min(x1, 63)}, yi[2] = {y0, min(y1, 63)}, zi[2] = {z0, min(z1, 63)};
    int o[8]; float w[8];
#pragma unroll
    for (int dz = 0; dz < 2; ++dz)
#pragma unroll
        for (int dy = 0; dy < 2; ++dy)
#pragma unroll
            for (int dx = 0; dx < 2; ++dx) {
                int tt = (dz << 2) | (dy << 1) | dx;
                w[tt] = (((fx[dx] * fy[dy]) * fz[dz]) * vx[dx]) * (vy[dy] * vz[dz]);
                o[tt] = (zi[dz] * 64 + yi[dy]) * 64 + xi[dx];
            }
    float acc = 0.0f;
#pragma unroll 2
    for (int c = 0; c < 16; ++c) {
        const float* ec = e + (size_t)c * 262144;
        const float* gc = g + (size_t)c * 262144;
        float ei = 0.0f, gi = 0.0f;
#pragma unroll
        for (int tt = 0; tt < 8; ++tt) {
            ei = ei + ec[o[tt]] * w[tt];
            gi = gi + gc[o[tt]] * w[tt];
        }
        acc += (gi >= 0.0f) ? ei : 0.0f;
    }
    return acc;
}

__global__ __launch_bounds__(256) void ctri_main_D(
    const float* __restrict__ coords,
    const float* __restrict__ lx,  const float* __restrict__ ly,  const float* __restrict__ lz,
    const float* __restrict__ lxg, const float* __restrict__ lyg, const float* __restrict__ lzg,
    const float* __restrict__ pxy, const float* __restrict__ pyz, const float* __restrict__ pxz,
    const float* __restrict__ pxyg, const float* __restrict__ pyzg, const float* __restrict__ pxzg,
    const float* __restrict__ vol, const float* __restrict__ volg,
    float* __restrict__ out, int P)
{
    float lc = block_line_const(lx, ly, lz, lxg, lyg, lzg);
    int p = blockIdx.x * blockDim.x + threadIdx.x;
    if (p >= P) return;
    float x = coords[3 * p + 0];
    float y = coords[3 * p + 1];
    float z = coords[3 * p + 2];
    float acc = lc;
    acc += sample_plane_pair_D(pxy, pxyg, x, y);
    acc += sample_plane_pair_D(pyz, pyzg, y, z);
    acc += sample_plane_pair_D(pxz, pxzg, x, z);
    acc += sample_volume_D(vol, volg, x, y, z);
    out[p] = acc;
}

// ---------------------------------------------------------------------------
extern "C" void kernel_launch(void* const* d_in, const int* in_sizes, int n_in,
                              void* d_out, int out_size, void* d_ws, size_t ws_size,
                              hipStream_t stream)
{
    (void)n_in; (void)out_size;
    const float* coords = (const float*)d_in[0];
    const float* pxy  = (const float*)d_in[1];
    const float* pyz  = (const float*)d_in[2];
    const float* pxz  = (const float*)d_in[3];
    const float* pxyg = (const float*)d_in[4];
    const float* pyzg = (const float*)d_in[5];
    const float* pxzg = (const float*)d_in[6];
    const float* lx   = (const float*)d_in[7];
    const float* ly   = (const float*)d_in[8];
    const float* lz   = (const float*)d_in[9];
    const float* lxg  = (const float*)d_in[10];
    const float* lyg  = (const float*)d_in[11];
    const float* lzg  = (const float*)d_in[12];
    const float* vol  = (const float*)d_in[13];
    const float* volg = (const float*)d_in[14];
    float* out = (float*)d_out;

    const int P = in_sizes[0] / 3;                        // 262144
    const size_t planeRec = (size_t)16384 * 192;          // 3 MB each
    const size_t volRec   = (size_t)262144 * 96;          // 24 MB
    const size_t tabBytes = 3 * planeRec + volRec;        // ~34.6 MB
    const size_t permBytes = (size_t)P * 4;               // 1 MB
    const size_t binBytes  = 512 * 4;
    const size_t need_bytes = tabBytes + permBytes + 2 * binBytes;

    const int pblocks = (P + 255) / 256;                  // 1024
    if (ws_size >= need_bytes) {
        char* tpxy = (char*)d_ws;
        char* tpyz = tpxy + planeRec;
        char* tpxz = tpyz + planeRec;
        char* tv   = tpxz + planeRec;
        u32* perm  = (u32*)(tv + volRec);
        u32* gcnt  = perm + P;
        u32* run   = gcnt + 512;

        prep_records<64, 64, 32, 192><<<256, 256, 0, stream>>>(pxy, pxyg, tpxy, 16384);
        prep_records<64, 64, 32, 192><<<256, 256, 0, stream>>>(pyz, pyzg, tpyz, 16384);
        prep_records<64, 64, 32, 192><<<256, 256, 0, stream>>>(pxz, pxzg, tpxz, 16384);
        prep_records<32, 128, 16, 96><<<2048, 256, 0, stream>>>(vol, volg, tv, 262144);

        bucket_zero<<<1, 512, 0, stream>>>(gcnt);
        bucket_count<<<pblocks, 256, 0, stream>>>(coords, gcnt, P);
        bucket_scan<<<1, 512, 0, stream>>>(gcnt, run);
        bucket_scatter<<<pblocks, 256, 0, stream>>>(coords, run, perm, P);

        const int mblocks = (P * 4 + 255) / 256;          // 4096, multiple of 8
        ctri_main_L<<<mblocks, 256, 0, stream>>>(coords, perm, lx, ly, lz, lxg, lyg, lzg,
                                                 tpxy, tpyz, tpxz, tv, out, P, mblocks);
    } else {
        ctri_main_D<<<pblocks, 256, 0, stream>>>(coords, lx, ly, lz, lxg, lyg, lzg,
                                                 pxy, pyz, pxz, pxyg, pyzg, pxzg,
                                                 vol, volg, out, P);
    }
}

// Round 8
// 226.724 us; speedup vs baseline: 4.0958x; 1.2838x over previous
//
#include <hip/hip_runtime.h>
#include <hip/hip_bf16.h>

#pragma clang fp contract(off)

typedef unsigned short u16;
typedef unsigned int u32;
typedef __attribute__((ext_vector_type(4))) float f32x4;
typedef __attribute__((ext_vector_type(8))) unsigned short u16x8;
typedef __attribute__((ext_vector_type(4))) unsigned short u16x4;

__device__ __forceinline__ float bf2f(u16 u) {
    union { unsigned int i; float f; } v; v.i = ((unsigned int)u) << 16; return v.f;
}
__device__ __forceinline__ u16 f2bf(float f) {
    __hip_bfloat16 h = __float2bfloat16(f);  // RNE
    return *(u16*)&h;
}

// ---------------------------------------------------------------------------
// Prep: packed per-position records [ECH x bf16 e | ECH x f32 g] (RECB bytes)
// from channel-major f32 e,g tables. LDS-tiled, coalesced loads.
// ---------------------------------------------------------------------------
template<int CC, int TP, int ECH, int RECB>
__global__ __launch_bounds__(256) void prep_records(
    const float* __restrict__ e, const float* __restrict__ g,
    char* __restrict__ dst, int HW)
{
    __shared__ float tile[CC][TP + 1];
    const int tbase = blockIdx.x * TP;
    const int t = threadIdx.x;
    constexpr int ITER = CC * TP / 256;
#pragma unroll
    for (int i = 0; i < ITER; ++i) {
        int eidx = i * 256 + t;
        int c  = eidx / TP;
        int pl = eidx % TP;
        const float* src = (c < CC / 2) ? e : g;
        int cs = (c < CC / 2) ? c : (c - CC / 2);
        tile[c][pl] = src[(size_t)cs * HW + tbase + pl];
    }
    __syncthreads();
#pragma unroll
    for (int i = 0; i < ITER; ++i) {
        int eidx = i * 256 + t;
        int pl = eidx / CC;
        int c  = eidx % CC;
        char* rec = dst + (size_t)(tbase + pl) * RECB;
        if (c < ECH)
            *(u16*)(rec + c * 2) = f2bf(tile[c][pl]);
        else
            *(float*)(rec + ECH * 2 + (c - ECH) * 4) = tile[c][pl];
    }
}

// ---------------------------------------------------------------------------
// Spatial bucketing: 8x8x8 = 512 cells, deterministic two-pass (no global
// returning atomics).
// ---------------------------------------------------------------------------
__device__ __forceinline__ int cell_of(float x, float y, float z)
{
    int cx = (int)fminf(fmaxf((x + 1.0f) * 4.0f, 0.0f), 7.0f);
    int cy = (int)fminf(fmaxf((y + 1.0f) * 4.0f, 0.0f), 7.0f);
    int cz = (int)fminf(fmaxf((z + 1.0f) * 4.0f, 0.0f), 7.0f);
    return cx + (cy << 3) + (cz << 6);
}

__global__ __launch_bounds__(512) void bucket_zero(u32* __restrict__ gcnt)
{
    gcnt[threadIdx.x] = 0u;
}

// per-block LDS histogram -> hist[b*512+c] (coalesced, full coverage) and
// fire-and-forget merge into global gcnt.
__global__ __launch_bounds__(256) void bucket_count(
    const float* __restrict__ coords, u32* __restrict__ gcnt,
    u32* __restrict__ hist, int P)
{
    __shared__ u32 h[512];
    int t = threadIdx.x;
    h[t] = 0u; h[t + 256] = 0u;
    __syncthreads();
    int p = blockIdx.x * 256 + t;
    if (p < P) {
        float x = coords[3 * p + 0];
        float y = coords[3 * p + 1];
        float z = coords[3 * p + 2];
        atomicAdd(&h[cell_of(x, y, z)], 1u);
    }
    __syncthreads();
    u32* hb = hist + (size_t)blockIdx.x * 512;
    hb[t] = h[t];
    hb[t + 256] = h[t + 256];
    if (h[t])       atomicAdd(&gcnt[t],       h[t]);
    if (h[t + 256]) atomicAdd(&gcnt[t + 256], h[t + 256]);
}

__global__ __launch_bounds__(512) void bucket_scan(
    const u32* __restrict__ gcnt, u32* __restrict__ run)
{
    __shared__ u32 s[512];
    int t = threadIdx.x;
    u32 mine = gcnt[t];
    s[t] = mine;
    __syncthreads();
#pragma unroll
    for (int off = 1; off < 512; off <<= 1) {
        u32 v = (t >= off) ? s[t - off] : 0u;
        __syncthreads();
        s[t] += v;
        __syncthreads();
    }
    run[t] = s[t] - mine;   // exclusive prefix
}

// base[b*512+c] = run[c] + sum_{b'<b} hist[b'*512+c].  One block per cell.
__global__ __launch_bounds__(256) void base_scan(
    const u32* __restrict__ hist, const u32* __restrict__ run,
    u32* __restrict__ base, int nb)
{
    int c = blockIdx.x;
    int t = threadIdx.x;
    int b0 = t * 4;
    u32 v[4];
#pragma unroll
    for (int i = 0; i < 4; ++i)
        v[i] = (b0 + i < nb) ? hist[(size_t)(b0 + i) * 512 + c] : 0u;
    u32 lsum = v[0] + v[1] + v[2] + v[3];
    __shared__ u32 ls[256];
    ls[t] = lsum;
    __syncthreads();
#pragma unroll
    for (int off = 1; off < 256; off <<= 1) {
        u32 x = (t >= off) ? ls[t - off] : 0u;
        __syncthreads();
        ls[t] += x;
        __syncthreads();
    }
    u32 acc = ls[t] - lsum + run[c];   // exclusive across blocks + cell base
#pragma unroll
    for (int i = 0; i < 4; ++i) {
        if (b0 + i < nb) base[(size_t)(b0 + i) * 512 + c] = acc;
        acc += v[i];
    }
}

// ranks via LDS returning atomics (uncontended), positions from base table.
__global__ __launch_bounds__(256) void bucket_scatter(
    const float* __restrict__ coords, const u32* __restrict__ base,
    u32* __restrict__ perm, int P)
{
    __shared__ u32 lh[512];
    int t = threadIdx.x;
    lh[t] = 0u; lh[t + 256] = 0u;
    __syncthreads();
    int p = blockIdx.x * 256 + t;
    if (p >= P) return;
    float x = coords[3 * p + 0];
    float y = coords[3 * p + 1];
    float z = coords[3 * p + 2];
    int cell = cell_of(x, y, z);
    u32 rank = atomicAdd(&lh[cell], 1u);
    u32 b = base[(size_t)blockIdx.x * 512 + cell];
    perm[b + rank] = (u32)p;
}

// ---------------------------------------------------------------------------
// Lane-split plane sampler: lane sub-index s (0..3) owns channels s*8..s*8+7.
// Record 192 B = [32 bf16 e | 32 f32 g]; g accumulated sequentially over taps
// 00,10,01,11 == reference association per channel.
// ---------------------------------------------------------------------------
__device__ __forceinline__ float plane_lane(
    const char* __restrict__ tp, float gx, float gy, int s)
{
    float ix = fminf(fmaxf((gx + 1.0f) * 0.5f * 127.0f, 0.0f), 127.0f);
    float iy = fminf(fmaxf((gy + 1.0f) * 0.5f * 127.0f, 0.0f), 127.0f);
    float x0f = floorf(ix), y0f = floorf(iy);
    float wx = ix - x0f, wy = iy - y0f;
    int x0 = (int)x0f, y0 = (int)y0f;
    int x1 = x0 + 1, y1 = y0 + 1;
    float vx1 = (x1 < 128) ? 1.0f : 0.0f;
    float vy1 = (y1 < 128) ? 1.0f : 0.0f;
    int x1c = min(x1, 127), y1c = min(y1, 127);
    float omwx = 1.0f - wx, omwy = 1.0f - wy;
    float ws4[4];
    ws4[0] = omwx * omwy;
    ws4[1] = (wx * omwy) * vx1;
    ws4[2] = (omwx * wy) * vy1;
    ws4[3] = ((wx * wy) * vx1) * vy1;
    unsigned o[4];
    o[0] = (unsigned)(y0  * 128 + x0 ) * 192u;
    o[1] = (unsigned)(y0  * 128 + x1c) * 192u;
    o[2] = (unsigned)(y1c * 128 + x0 ) * 192u;
    o[3] = (unsigned)(y1c * 128 + x1c) * 192u;

    const int eoff = s * 16;
    const int goff = 64 + s * 32;
    f32x4 ea0 = {0.0f, 0.0f, 0.0f, 0.0f}, ea1 = {0.0f, 0.0f, 0.0f, 0.0f};
    f32x4 ga0 = {0.0f, 0.0f, 0.0f, 0.0f}, ga1 = {0.0f, 0.0f, 0.0f, 0.0f};
#pragma unroll
    for (int t = 0; t < 4; ++t) {
        const char* bp = tp + o[t];
        float w = ws4[t];
        u16x8 ev = *(const u16x8*)(bp + eoff);
        f32x4 g0 = *(const f32x4*)(bp + goff);
        f32x4 g1 = *(const f32x4*)(bp + goff + 16);
#pragma unroll
        for (int j = 0; j < 4; ++j) {
            ga0[j] = ga0[j] + g0[j] * w;
            ga1[j] = ga1[j] + g1[j] * w;
            ea0[j] = ea0[j] + bf2f(ev[j]) * w;
            ea1[j] = ea1[j] + bf2f(ev[j + 4]) * w;
        }
    }
    float acc = 0.0f;
#pragma unroll
    for (int j = 0; j < 4; ++j) {
        acc += (ga0[j] >= 0.0f) ? ea0[j] : 0.0f;
        acc += (ga1[j] >= 0.0f) ? ea1[j] : 0.0f;
    }
    return acc;
}

// ---------------------------------------------------------------------------
// Lane-split volume sampler: lane s owns channels s*4..s*4+3.
// Record 96 B = [16 bf16 e | 16 f32 g]; reference tt order (dz major).
// ---------------------------------------------------------------------------
__device__ __forceinline__ float vol_lane(
    const char* __restrict__ tv, float gx, float gy, float gz, int s)
{
    float ix = fminf(fmaxf((gx + 1.0f) * 0.5f * 63.0f, 0.0f), 63.0f);
    float iy = fminf(fmaxf((gy + 1.0f) * 0.5f * 63.0f, 0.0f), 63.0f);
    float iz = fminf(fmaxf((gz + 1.0f) * 0.5f * 63.0f, 0.0f), 63.0f);
    float x0f = floorf(ix), y0f = floorf(iy), z0f = floorf(iz);
    float wx = ix - x0f, wy = iy - y0f, wz = iz - z0f;
    int x0 = (int)x0f, y0 = (int)y0f, z0 = (int)z0f;
    int x1 = x0 + 1, y1 = y0 + 1, z1 = z0 + 1;
    float fx[2] = {1.0f - wx, wx}, fy[2] = {1.0f - wy, wy}, fz[2] = {1.0f - wz, wz};
    float vx[2] = {1.0f, (x1 < 64) ? 1.0f : 0.0f};
    float vy[2] = {1.0f, (y1 < 64) ? 1.0f : 0.0f};
    float vz[2] = {1.0f, (z1 < 64) ? 1.0f : 0.0f};
    int xi[2] = {x0, min(x1, 63)}, yi[2] = {y0, min(y1, 63)}, zi[2] = {z0, min(z1, 63)};

    unsigned off[8];
    float w[8];
#pragma unroll
    for (int dz = 0; dz < 2; ++dz)
#pragma unroll
        for (int dy = 0; dy < 2; ++dy)
#pragma unroll
            for (int dx = 0; dx < 2; ++dx) {
                int tt = (dz << 2) | (dy << 1) | dx;   // reference add order
                w[tt] = (((fx[dx] * fy[dy]) * fz[dz]) * vx[dx]) * (vy[dy] * vz[dz]);
                off[tt] = (unsigned)((zi[dz] * 64 + yi[dy]) * 64 + xi[dx]) * 96u;
            }
    const int eoff = s * 8;
    const int goff = 32 + s * 16;
    f32x4 ea = {0.0f, 0.0f, 0.0f, 0.0f}, ga = {0.0f, 0.0f, 0.0f, 0.0f};
#pragma unroll
    for (int tt = 0; tt < 8; ++tt) {
        const char* bp = tv + off[tt];
        float wt = w[tt];
        u16x4 ev = *(const u16x4*)(bp + eoff);
        f32x4 gv = *(const f32x4*)(bp + goff);
#pragma unroll
        for (int j = 0; j < 4; ++j) {
            ga[j] = ga[j] + gv[j] * wt;
            ea[j] = ea[j] + bf2f(ev[j]) * wt;
        }
    }
    float acc = 0.0f;
#pragma unroll
    for (int j = 0; j < 4; ++j)
        acc += (ga[j] >= 0.0f) ? ea[j] : 0.0f;
    return acc;
}

// ---------------------------------------------------------------------------
// Line term: constant across points (W=1 -> ix=0 wx=0; gy=0 -> iy=63.5)
// ---------------------------------------------------------------------------
__device__ __forceinline__ float line_pair(const float* __restrict__ e,
                                           const float* __restrict__ g, int c)
{
    float ev = e[c * 128 + 63] * 0.5f + e[c * 128 + 64] * 0.5f;
    float gv = g[c * 128 + 63] * 0.5f + g[c * 128 + 64] * 0.5f;
    return (gv >= 0.0f) ? ev : 0.0f;
}

__device__ __forceinline__ float block_line_const(
    const float* lx, const float* ly, const float* lz,
    const float* lxg, const float* lyg, const float* lzg)
{
    __shared__ float lc_sh;
    int t = threadIdx.x;
    if (t < 64) {
        float part = line_pair(lx, lxg, t) + line_pair(ly, lyg, t) + line_pair(lz, lzg, t);
#pragma unroll
        for (int off = 32; off > 0; off >>= 1) part += __shfl_down(part, off);
        if (t == 0) lc_sh = part;
    }
    __syncthreads();
    return lc_sh;
}

// ---------------------------------------------------------------------------
// Main kernel: 4 lanes per point, bucketed order + XCD-contiguous swizzle.
// ---------------------------------------------------------------------------
__global__ __launch_bounds__(256) void ctri_main_L(
    const float* __restrict__ coords, const u32* __restrict__ perm,
    const float* __restrict__ lx,  const float* __restrict__ ly,  const float* __restrict__ lz,
    const float* __restrict__ lxg, const float* __restrict__ lyg, const float* __restrict__ lzg,
    const char* __restrict__ tpxy, const char* __restrict__ tpyz, const char* __restrict__ tpxz,
    const char* __restrict__ tv,
    float* __restrict__ out, int P, int nblk)
{
    float lc = block_line_const(lx, ly, lz, lxg, lyg, lzg);
    int b = blockIdx.x;
    int cpx = nblk >> 3;                 // nblk multiple of 8
    int swz = (b & 7) * cpx + (b >> 3);  // XCD k <- contiguous perm chunk
    int i = swz * 64 + (threadIdx.x >> 2);
    int s = threadIdx.x & 3;
    if (i >= P) return;
    int p = (int)perm[i];
    float x = coords[3 * p + 0];
    float y = coords[3 * p + 1];
    float z = coords[3 * p + 2];
    float part = 0.0f;
    part += plane_lane(tpxy, x, y, s);
    part += plane_lane(tpyz, y, z, s);
    part += plane_lane(tpxz, x, z, s);
    part += vol_lane(tv, x, y, z, s);
    part += __shfl_xor(part, 1, 64);
    part += __shfl_xor(part, 2, 64);
    if (s == 0) out[p] = lc + part;
}

// ---------------------------------------------------------------------------
// Direct-layout f32 fallback (used only if ws_size too small)
// ---------------------------------------------------------------------------
__device__ __forceinline__ float sample_plane_pair_D(
    const float* __restrict__ e, const float* __restrict__ g, float gx, float gy)
{
    float ix = fminf(fmaxf((gx + 1.0f) * 0.5f * 127.0f, 0.0f), 127.0f);
    float iy = fminf(fmaxf((gy + 1.0f) * 0.5f * 127.0f, 0.0f), 127.0f);
    float x0f = floorf(ix), y0f = floorf(iy);
    float wx = ix - x0f, wy = iy - y0f;
    int x0 = (int)x0f, y0 = (int)y0f;
    int x1 = x0 + 1, y1 = y0 + 1;
    float vx1 = (x1 < 128) ? 1.0f : 0.0f;
    float vy1 = (y1 < 128) ? 1.0f : 0.0f;
    int x1c = min(x1, 127), y1c = min(y1, 127);
    float omwx = 1.0f - wx, omwy = 1.0f - wy;
    float w00 = omwx * omwy;
    float w10 = (wx * omwy) * vx1;
    float w01 = (omwx * wy) * vy1;
    float w11 = ((wx * wy) * vx1) * vy1;
    int o00 = y0 * 128 + x0, o10 = y0 * 128 + x1c;
    int o01 = y1c * 128 + x0, o11 = y1c * 128 + x1c;
    float acc = 0.0f;
#pragma unroll 4
    for (int c = 0; c < 32; ++c) {
        const float* ec = e + (size_t)c * 16384;
        const float* gc = g + (size_t)c * 16384;
        float ei = ((ec[o00] * w00 + ec[o10] * w10) + ec[o01] * w01) + ec[o11] * w11;
        float gi = ((gc[o00] * w00 + gc[o10] * w10) + gc[o01] * w01) + gc[o11] * w11;
        acc += (gi >= 0.0f) ? ei : 0.0f;
    }
    return acc;
}

__device__ __forceinline__ float sample_volume_D(
    const float* __restrict__ e, const float* __restrict__ g,
    float gx, float gy, float gz)
{
    float ix = fminf(fmaxf((gx + 1.0f) * 0.5f * 63.0f, 0.0f), 63.0f);
    float iy = fminf(fmaxf((gy + 1.0f) * 0.5f * 63.0f, 0.0f), 63.0f);
    float iz = fminf(fmaxf((gz + 1.0f) * 0.5f * 63.0f, 0.0f), 63.0f);
    float x0f = floorf(ix), y0f = floorf(iy), z0f = floorf(iz);
    float wx = ix - x0f, wy = iy - y0f, wz = iz - z0f;
    int x0 = (int)x0f, y0 = (int)y0f, z0 = (int)z0f;
    int x1 = x0 + 1, y1 = y0 + 1, z1 = z0 + 1;
    float fx[2] = {1.0f - wx, wx}, fy[2] = {1.0f - wy, wy}, fz[2] = {1.0f - wz, wz};
    float vx[2] = {1.0f, (x1 < 64) ? 1.0f : 0.0f};
    float vy[2] = {1.0f, (y1 < 64) ? 1.0f : 0.0f};
    float vz[2] = {1.0f, (z1 < 64) ? 1.0f : 0.0f};
    int xi[2] = {x0, min(x1, 63)}, yi[2] = {y0, min(y1, 63)}, zi[2] = {z0, min(z1, 63)};
    int o[8]; float w[8];
#pragma unroll
    for (int dz = 0; dz < 2; ++dz)
#pragma unroll
        for (int dy = 0; dy < 2; ++dy)
#pragma unroll
            for (int dx = 0; dx < 2; ++dx) {
                int tt = (dz << 2) | (dy << 1) | dx;
                w[tt] = (((fx[dx] * fy[dy]) * fz[dz]) * vx[dx]) * (vy[dy] * vz[dz]);
                o[tt] = (zi[dz] * 64 + yi[dy]) * 64 + xi[dx];
            }
    float acc = 0.0f;
#pragma unroll 2
    for (int c = 0; c < 16; ++c) {
        const float* ec = e + (size_t)c * 262144;
        const float* gc = g + (size_t)c * 262144;
        float ei = 0.0f, gi = 0.0f;
#pragma unroll
        for (int tt = 0; tt < 8; ++tt) {
            ei = ei + ec[o[tt]] * w[tt];
            gi = gi + gc[o[tt]] * w[tt];
        }
        acc += (gi >= 0.0f) ? ei : 0.0f;
    }
    return acc;
}

__global__ __launch_bounds__(256) void ctri_main_D(
    const float* __restrict__ coords,
    const float* __restrict__ lx,  const float* __restrict__ ly,  const float* __restrict__ lz,
    const float* __restrict__ lxg, const float* __restrict__ lyg, const float* __restrict__ lzg,
    const float* __restrict__ pxy, const float* __restrict__ pyz, const float* __restrict__ pxz,
    const float* __restrict__ pxyg, const float* __restrict__ pyzg, const float* __restrict__ pxzg,
    const float* __restrict__ vol, const float* __restrict__ volg,
    float* __restrict__ out, int P)
{
    float lc = block_line_const(lx, ly, lz, lxg, lyg, lzg);
    int p = blockIdx.x * blockDim.x + threadIdx.x;
    if (p >= P) return;
    float x = coords[3 * p + 0];
    float y = coords[3 * p + 1];
    float z = coords[3 * p + 2];
    float acc = lc;
    acc += sample_plane_pair_D(pxy, pxyg, x, y);
    acc += sample_plane_pair_D(pyz, pyzg, y, z);
    acc += sample_plane_pair_D(pxz, pxzg, x, z);
    acc += sample_volume_D(vol, volg, x, y, z);
    out[p] = acc;
}

// ---------------------------------------------------------------------------
extern "C" void kernel_launch(void* const* d_in, const int* in_sizes, int n_in,
                              void* d_out, int out_size, void* d_ws, size_t ws_size,
                              hipStream_t stream)
{
    (void)n_in; (void)out_size;
    const float* coords = (const float*)d_in[0];
    const float* pxy  = (const float*)d_in[1];
    const float* pyz  = (const float*)d_in[2];
    const float* pxz  = (const float*)d_in[3];
    const float* pxyg = (const float*)d_in[4];
    const float* pyzg = (const float*)d_in[5];
    const float* pxzg = (const float*)d_in[6];
    const float* lx   = (const float*)d_in[7];
    const float* ly   = (const float*)d_in[8];
    const float* lz   = (const float*)d_in[9];
    const float* lxg  = (const float*)d_in[10];
    const float* lyg  = (const float*)d_in[11];
    const float* lzg  = (const float*)d_in[12];
    const float* vol  = (const float*)d_in[13];
    const float* volg = (const float*)d_in[14];
    float* out = (float*)d_out;

    const int P = in_sizes[0] / 3;                        // 262144
    const int pblocks = (P + 255) / 256;                  // 1024
    const size_t planeRec = (size_t)16384 * 192;          // 3 MB each
    const size_t volRec   = (size_t)262144 * 96;          // 24 MB
    const size_t tabBytes = 3 * planeRec + volRec;        // ~34.6 MB
    const size_t permBytes = (size_t)P * 4;               // 1 MB
    const size_t histBytes = (size_t)pblocks * 512 * 4;   // 2 MB
    const size_t binBytes  = 512 * 4;
    const size_t need_bytes = tabBytes + permBytes + 2 * histBytes + 2 * binBytes;

    if (ws_size >= need_bytes) {
        char* tpxy = (char*)d_ws;
        char* tpyz = tpxy + planeRec;
        char* tpxz = tpyz + planeRec;
        char* tv   = tpxz + planeRec;
        u32* perm  = (u32*)(tv + volRec);
        u32* hist  = perm + P;
        u32* base  = hist + (size_t)pblocks * 512;
        u32* gcnt  = base + (size_t)pblocks * 512;
        u32* run   = gcnt + 512;

        prep_records<64, 64, 32, 192><<<256, 256, 0, stream>>>(pxy, pxyg, tpxy, 16384);
        prep_records<64, 64, 32, 192><<<256, 256, 0, stream>>>(pyz, pyzg, tpyz, 16384);
        prep_records<64, 64, 32, 192><<<256, 256, 0, stream>>>(pxz, pxzg, tpxz, 16384);
        prep_records<32, 128, 16, 96><<<2048, 256, 0, stream>>>(vol, volg, tv, 262144);

        bucket_zero<<<1, 512, 0, stream>>>(gcnt);
        bucket_count<<<pblocks, 256, 0, stream>>>(coords, gcnt, hist, P);
        bucket_scan<<<1, 512, 0, stream>>>(gcnt, run);
        base_scan<<<512, 256, 0, stream>>>(hist, run, base, pblocks);
        bucket_scatter<<<pblocks, 256, 0, stream>>>(coords, base, perm, P);

        const int mblocks = (P * 4 + 255) / 256;          // 4096, multiple of 8
        ctri_main_L<<<mblocks, 256, 0, stream>>>(coords, perm, lx, ly, lz, lxg, lyg, lzg,
                                                 tpxy, tpyz, tpxz, tv, out, P, mblocks);
    } else {
        ctri_main_D<<<pblocks, 256, 0, stream>>>(coords, lx, ly, lz, lxg, lyg, lzg,
                                                 pxy, pyz, pxz, pxyg, pyzg, pxzg,
                                                 vol, volg, out, P);
    }
}

// Round 9
// 196.868 us; speedup vs baseline: 4.7170x; 1.1517x over previous
//
#include <hip/hip_runtime.h>
#include <hip/hip_bf16.h>

#pragma clang fp contract(off)

typedef unsigned short u16;
typedef unsigned int u32;
typedef __attribute__((ext_vector_type(4))) float f32x4;
typedef __attribute__((ext_vector_type(8))) unsigned short u16x8;
typedef __attribute__((ext_vector_type(4))) unsigned short u16x4;

__device__ __forceinline__ float bf2f(u16 u) {
    union { unsigned int i; float f; } v; v.i = ((unsigned int)u) << 16; return v.f;
}
__device__ __forceinline__ u16 f2bf(float f) {
    __hip_bfloat16 h = __float2bfloat16(f);  // RNE
    return *(u16*)&h;
}

__device__ __forceinline__ int cell_of(float x, float y, float z)
{
    int cx = (int)fminf(fmaxf((x + 1.0f) * 4.0f, 0.0f), 7.0f);
    int cy = (int)fminf(fmaxf((y + 1.0f) * 4.0f, 0.0f), 7.0f);
    int cz = (int)fminf(fmaxf((z + 1.0f) * 4.0f, 0.0f), 7.0f);
    return cx + (cy << 3) + (cz << 6);
}

// ---------------------------------------------------------------------------
// Fused prep + histogram kernel.
//   blocks [0,768):   plane record prep (which = b>>8), CC=64 TP=64 ECH=32 RECB=192
//   blocks [768,2816): volume record prep,              CC=32 TP=128 ECH=16 RECB=96
//   blocks [2816,3840): per-block 512-cell histogram of coords -> hist
// Record: [ECH x bf16 e | ECH x f32 g]. ITER = CC*TP/256 = 16 in both preps.
// ---------------------------------------------------------------------------
__global__ __launch_bounds__(256) void fused_prep_count(
    const float* __restrict__ pxy, const float* __restrict__ pxyg,
    const float* __restrict__ pyz, const float* __restrict__ pyzg,
    const float* __restrict__ pxz, const float* __restrict__ pxzg,
    const float* __restrict__ vol, const float* __restrict__ volg,
    char* __restrict__ tpxy, char* __restrict__ tpyz, char* __restrict__ tpxz,
    char* __restrict__ tv,
    const float* __restrict__ coords, u32* __restrict__ hist, int P)
{
    __shared__ float smem[4160];          // 64*65 floats (>= 32*129)
    const int b = blockIdx.x;
    const int t = threadIdx.x;

    if (b < 2816) {
        const float *e, *g; char* dst;
        int HW, tplog, cclog, ECH, RECB, blk;
        if (b < 768) {
            int which = b >> 8; blk = b & 255;
            e   = (which == 0) ? pxy  : (which == 1) ? pyz  : pxz;
            g   = (which == 0) ? pxyg : (which == 1) ? pyzg : pxzg;
            dst = (which == 0) ? tpxy : (which == 1) ? tpyz : tpxz;
            HW = 16384; tplog = 6; cclog = 6; ECH = 32; RECB = 192;
        } else {
            blk = b - 768; e = vol; g = volg; dst = tv;
            HW = 262144; tplog = 7; cclog = 5; ECH = 16; RECB = 96;
        }
        const int TP = 1 << tplog, CC = 1 << cclog, half = CC >> 1;
        const int stride = TP + 1;
        const int tbase = blk * TP;
#pragma unroll
        for (int i = 0; i < 16; ++i) {
            int eidx = i * 256 + t;
            int c  = eidx >> tplog;
            int pl = eidx & (TP - 1);
            const float* src = (c < half) ? e : g;
            int cs = (c < half) ? c : (c - half);
            smem[c * stride + pl] = src[(size_t)cs * HW + tbase + pl];
        }
        __syncthreads();
#pragma unroll
        for (int i = 0; i < 16; ++i) {
            int eidx = i * 256 + t;
            int pl = eidx >> cclog;
            int c  = eidx & (CC - 1);
            char* rec = dst + (size_t)(tbase + pl) * RECB;
            float v = smem[c * stride + pl];
            if (c < ECH)
                *(u16*)(rec + c * 2) = f2bf(v);
            else
                *(float*)(rec + ECH * 2 + (c - ECH) * 4) = v;
        }
    } else {
        u32* h = (u32*)smem;
        int blk = b - 2816;
        h[t] = 0u; h[t + 256] = 0u;
        __syncthreads();
        int p = blk * 256 + t;
        if (p < P) {
            float x = coords[3 * p + 0];
            float y = coords[3 * p + 1];
            float z = coords[3 * p + 2];
            atomicAdd(&h[cell_of(x, y, z)], 1u);
        }
        __syncthreads();
        u32* hb = hist + (size_t)blk * 512;
        hb[t] = h[t];
        hb[t + 256] = h[t + 256];
    }
}

// ---------------------------------------------------------------------------
// Per-cell exclusive scan across blocks: base[b*512+c] = sum_{b'<b} hist[b'][c]
// (NO cell offset), totals[c] = cell total. One block per cell, nb = 1024.
// ---------------------------------------------------------------------------
__global__ __launch_bounds__(256) void cell_base(
    const u32* __restrict__ hist, u32* __restrict__ base,
    u32* __restrict__ totals, int nb)
{
    int c = blockIdx.x;
    int t = threadIdx.x;
    int b0 = t * 4;
    u32 v[4];
#pragma unroll
    for (int i = 0; i < 4; ++i)
        v[i] = (b0 + i < nb) ? hist[(size_t)(b0 + i) * 512 + c] : 0u;
    u32 lsum = v[0] + v[1] + v[2] + v[3];
    __shared__ u32 ls[256];
    ls[t] = lsum;
    __syncthreads();
#pragma unroll
    for (int off = 1; off < 256; off <<= 1) {
        u32 x = (t >= off) ? ls[t - off] : 0u;
        __syncthreads();
        ls[t] += x;
        __syncthreads();
    }
    u32 acc = ls[t] - lsum;   // exclusive across blocks
#pragma unroll
    for (int i = 0; i < 4; ++i) {
        if (b0 + i < nb) base[(size_t)(b0 + i) * 512 + c] = acc;
        acc += v[i];
    }
    if (t == 255) totals[c] = acc;
}

// ---------------------------------------------------------------------------
// Scatter: per-block local 512-entry exclusive scan of cell totals (LDS),
// intra-block ranks via uncontended LDS atomics, no global returning atomics.
// perm order identical to two-pass reference construction.
// ---------------------------------------------------------------------------
__global__ __launch_bounds__(256) void bucket_scatter2(
    const float* __restrict__ coords, const u32* __restrict__ base,
    const u32* __restrict__ totals, u32* __restrict__ perm, int P)
{
    __shared__ u32 lh[512];
    __shared__ u32 ts[512];
    __shared__ u32 torig[512];
    int t = threadIdx.x;
    lh[t] = 0u; lh[t + 256] = 0u;
    u32 a0 = totals[t], a1 = totals[t + 256];
    ts[t] = a0; ts[t + 256] = a1;
    torig[t] = a0; torig[t + 256] = a1;
    __syncthreads();
#pragma unroll
    for (int off = 1; off < 512; off <<= 1) {
        u32 x0 = (t >= off) ? ts[t - off] : 0u;
        u32 x1 = (t + 256 >= off) ? ts[t + 256 - off] : 0u;
        __syncthreads();
        ts[t] += x0; ts[t + 256] += x1;
        __syncthreads();
    }
    ts[t]       -= torig[t];        // inclusive -> exclusive
    ts[t + 256] -= torig[t + 256];
    __syncthreads();

    int p = blockIdx.x * 256 + t;
    if (p < P) {
        float x = coords[3 * p + 0];
        float y = coords[3 * p + 1];
        float z = coords[3 * p + 2];
        int cell = cell_of(x, y, z);
        u32 rank = atomicAdd(&lh[cell], 1u);
        u32 pos = ts[cell] + base[(size_t)blockIdx.x * 512 + cell] + rank;
        perm[pos] = (u32)p;
    }
}

// ---------------------------------------------------------------------------
// Lane-split plane sampler: lane sub-index s (0..3) owns channels s*8..s*8+7.
// Record 192 B = [32 bf16 e | 32 f32 g]; g accumulated sequentially over taps
// 00,10,01,11 == reference association per channel.
// ---------------------------------------------------------------------------
__device__ __forceinline__ float plane_lane(
    const char* __restrict__ tp, float gx, float gy, int s)
{
    float ix = fminf(fmaxf((gx + 1.0f) * 0.5f * 127.0f, 0.0f), 127.0f);
    float iy = fminf(fmaxf((gy + 1.0f) * 0.5f * 127.0f, 0.0f), 127.0f);
    float x0f = floorf(ix), y0f = floorf(iy);
    float wx = ix - x0f, wy = iy - y0f;
    int x0 = (int)x0f, y0 = (int)y0f;
    int x1 = x0 + 1, y1 = y0 + 1;
    float vx1 = (x1 < 128) ? 1.0f : 0.0f;
    float vy1 = (y1 < 128) ? 1.0f : 0.0f;
    int x1c = min(x1, 127), y1c = min(y1, 127);
    float omwx = 1.0f - wx, omwy = 1.0f - wy;
    float ws4[4];
    ws4[0] = omwx * omwy;
    ws4[1] = (wx * omwy) * vx1;
    ws4[2] = (omwx * wy) * vy1;
    ws4[3] = ((wx * wy) * vx1) * vy1;
    unsigned o[4];
    o[0] = (unsigned)(y0  * 128 + x0 ) * 192u;
    o[1] = (unsigned)(y0  * 128 + x1c) * 192u;
    o[2] = (unsigned)(y1c * 128 + x0 ) * 192u;
    o[3] = (unsigned)(y1c * 128 + x1c) * 192u;

    const int eoff = s * 16;
    const int goff = 64 + s * 32;
    f32x4 ea0 = {0.0f, 0.0f, 0.0f, 0.0f}, ea1 = {0.0f, 0.0f, 0.0f, 0.0f};
    f32x4 ga0 = {0.0f, 0.0f, 0.0f, 0.0f}, ga1 = {0.0f, 0.0f, 0.0f, 0.0f};
#pragma unroll
    for (int t = 0; t < 4; ++t) {
        const char* bp = tp + o[t];
        float w = ws4[t];
        u16x8 ev = *(const u16x8*)(bp + eoff);
        f32x4 g0 = *(const f32x4*)(bp + goff);
        f32x4 g1 = *(const f32x4*)(bp + goff + 16);
#pragma unroll
        for (int j = 0; j < 4; ++j) {
            ga0[j] = ga0[j] + g0[j] * w;
            ga1[j] = ga1[j] + g1[j] * w;
            ea0[j] = ea0[j] + bf2f(ev[j]) * w;
            ea1[j] = ea1[j] + bf2f(ev[j + 4]) * w;
        }
    }
    float acc = 0.0f;
#pragma unroll
    for (int j = 0; j < 4; ++j) {
        acc += (ga0[j] >= 0.0f) ? ea0[j] : 0.0f;
        acc += (ga1[j] >= 0.0f) ? ea1[j] : 0.0f;
    }
    return acc;
}

// ---------------------------------------------------------------------------
// Lane-split volume sampler: lane s owns channels s*4..s*4+3.
// Record 96 B = [16 bf16 e | 16 f32 g]; reference tt order (dz major).
// ---------------------------------------------------------------------------
__device__ __forceinline__ float vol_lane(
    const char* __restrict__ tv, float gx, float gy, float gz, int s)
{
    float ix = fminf(fmaxf((gx + 1.0f) * 0.5f * 63.0f, 0.0f), 63.0f);
    float iy = fminf(fmaxf((gy + 1.0f) * 0.5f * 63.0f, 0.0f), 63.0f);
    float iz = fminf(fmaxf((gz + 1.0f) * 0.5f * 63.0f, 0.0f), 63.0f);
    float x0f = floorf(ix), y0f = floorf(iy), z0f = floorf(iz);
    float wx = ix - x0f, wy = iy - y0f, wz = iz - z0f;
    int x0 = (int)x0f, y0 = (int)y0f, z0 = (int)z0f;
    int x1 = x0 + 1, y1 = y0 + 1, z1 = z0 + 1;
    float fx[2] = {1.0f - wx, wx}, fy[2] = {1.0f - wy, wy}, fz[2] = {1.0f - wz, wz};
    float vx[2] = {1.0f, (x1 < 64) ? 1.0f : 0.0f};
    float vy[2] = {1.0f, (y1 < 64) ? 1.0f : 0.0f};
    float vz[2] = {1.0f, (z1 < 64) ? 1.0f : 0.0f};
    int xi[2] = {x0, min(x1, 63)}, yi[2] = {y0, min(y1, 63)}, zi[2] = {z0, min(z1, 63)};

    unsigned off[8];
    float w[8];
#pragma unroll
    for (int dz = 0; dz < 2; ++dz)
#pragma unroll
        for (int dy = 0; dy < 2; ++dy)
#pragma unroll
            for (int dx = 0; dx < 2; ++dx) {
                int tt = (dz << 2) | (dy << 1) | dx;   // reference add order
                w[tt] = (((fx[dx] * fy[dy]) * fz[dz]) * vx[dx]) * (vy[dy] * vz[dz]);
                off[tt] = (unsigned)((zi[dz] * 64 + yi[dy]) * 64 + xi[dx]) * 96u;
            }
    const int eoff = s * 8;
    const int goff = 32 + s * 16;
    f32x4 ea = {0.0f, 0.0f, 0.0f, 0.0f}, ga = {0.0f, 0.0f, 0.0f, 0.0f};
#pragma unroll
    for (int tt = 0; tt < 8; ++tt) {
        const char* bp = tv + off[tt];
        float wt = w[tt];
        u16x4 ev = *(const u16x4*)(bp + eoff);
        f32x4 gv = *(const f32x4*)(bp + goff);
#pragma unroll
        for (int j = 0; j < 4; ++j) {
            ga[j] = ga[j] + gv[j] * wt;
            ea[j] = ea[j] + bf2f(ev[j]) * wt;
        }
    }
    float acc = 0.0f;
#pragma unroll
    for (int j = 0; j < 4; ++j)
        acc += (ga[j] >= 0.0f) ? ea[j] : 0.0f;
    return acc;
}

// ---------------------------------------------------------------------------
// Line term: constant across points (W=1 -> ix=0 wx=0; gy=0 -> iy=63.5)
// ---------------------------------------------------------------------------
__device__ __forceinline__ float line_pair(const float* __restrict__ e,
                                           const float* __restrict__ g, int c)
{
    float ev = e[c * 128 + 63] * 0.5f + e[c * 128 + 64] * 0.5f;
    float gv = g[c * 128 + 63] * 0.5f + g[c * 128 + 64] * 0.5f;
    return (gv >= 0.0f) ? ev : 0.0f;
}

__device__ __forceinline__ float block_line_const(
    const float* lx, const float* ly, const float* lz,
    const float* lxg, const float* lyg, const float* lzg)
{
    __shared__ float lc_sh;
    int t = threadIdx.x;
    if (t < 64) {
        float part = line_pair(lx, lxg, t) + line_pair(ly, lyg, t) + line_pair(lz, lzg, t);
#pragma unroll
        for (int off = 32; off > 0; off >>= 1) part += __shfl_down(part, off);
        if (t == 0) lc_sh = part;
    }
    __syncthreads();
    return lc_sh;
}

// ---------------------------------------------------------------------------
// Main kernel: 4 lanes per point, bucketed order + XCD-contiguous swizzle.
// ---------------------------------------------------------------------------
__global__ __launch_bounds__(256) void ctri_main_L(
    const float* __restrict__ coords, const u32* __restrict__ perm,
    const float* __restrict__ lx,  const float* __restrict__ ly,  const float* __restrict__ lz,
    const float* __restrict__ lxg, const float* __restrict__ lyg, const float* __restrict__ lzg,
    const char* __restrict__ tpxy, const char* __restrict__ tpyz, const char* __restrict__ tpxz,
    const char* __restrict__ tv,
    float* __restrict__ out, int P, int nblk)
{
    float lc = block_line_const(lx, ly, lz, lxg, lyg, lzg);
    int b = blockIdx.x;
    int cpx = nblk >> 3;                 // nblk multiple of 8
    int swz = (b & 7) * cpx + (b >> 3);  // XCD k <- contiguous perm chunk
    int i = swz * 64 + (threadIdx.x >> 2);
    int s = threadIdx.x & 3;
    if (i >= P) return;
    int p = (int)perm[i];
    float x = coords[3 * p + 0];
    float y = coords[3 * p + 1];
    float z = coords[3 * p + 2];
    float part = 0.0f;
    part += plane_lane(tpxy, x, y, s);
    part += plane_lane(tpyz, y, z, s);
    part += plane_lane(tpxz, x, z, s);
    part += vol_lane(tv, x, y, z, s);
    part += __shfl_xor(part, 1, 64);
    part += __shfl_xor(part, 2, 64);
    if (s == 0) out[p] = lc + part;
}

// ---------------------------------------------------------------------------
// Direct-layout f32 fallback (used only if ws_size too small)
// ---------------------------------------------------------------------------
__device__ __forceinline__ float sample_plane_pair_D(
    const float* __restrict__ e, const float* __restrict__ g, float gx, float gy)
{
    float ix = fminf(fmaxf((gx + 1.0f) * 0.5f * 127.0f, 0.0f), 127.0f);
    float iy = fminf(fmaxf((gy + 1.0f) * 0.5f * 127.0f, 0.0f), 127.0f);
    float x0f = floorf(ix), y0f = floorf(iy);
    float wx = ix - x0f, wy = iy - y0f;
    int x0 = (int)x0f, y0 = (int)y0f;
    int x1 = x0 + 1, y1 = y0 + 1;
    float vx1 = (x1 < 128) ? 1.0f : 0.0f;
    float vy1 = (y1 < 128) ? 1.0f : 0.0f;
    int x1c = min(x1, 127), y1c = min(y1, 127);
    float omwx = 1.0f - wx, omwy = 1.0f - wy;
    float w00 = omwx * omwy;
    float w10 = (wx * omwy) * vx1;
    float w01 = (omwx * wy) * vy1;
    float w11 = ((wx * wy) * vx1) * vy1;
    int o00 = y0 * 128 + x0, o10 = y0 * 128 + x1c;
    int o01 = y1c * 128 + x0, o11 = y1c * 128 + x1c;
    float acc = 0.0f;
#pragma unroll 4
    for (int c = 0; c < 32; ++c) {
        const float* ec = e + (size_t)c * 16384;
        const float* gc = g + (size_t)c * 16384;
        float ei = ((ec[o00] * w00 + ec[o10] * w10) + ec[o01] * w01) + ec[o11] * w11;
        float gi = ((gc[o00] * w00 + gc[o10] * w10) + gc[o01] * w01) + gc[o11] * w11;
        acc += (gi >= 0.0f) ? ei : 0.0f;
    }
    return acc;
}

__device__ __forceinline__ float sample_volume_D(
    const float* __restrict__ e, const float* __restrict__ g,
    float gx, float gy, float gz)
{
    float ix = fminf(fmaxf((gx + 1.0f) * 0.5f * 63.0f, 0.0f), 63.0f);
    float iy = fminf(fmaxf((gy + 1.0f) * 0.5f * 63.0f, 0.0f), 63.0f);
    float iz = fminf(fmaxf((gz + 1.0f) * 0.5f * 63.0f, 0.0f), 63.0f);
    float x0f = floorf(ix), y0f = floorf(iy), z0f = floorf(iz);
    float wx = ix - x0f, wy = iy - y0f, wz = iz - z0f;
    int x0 = (int)x0f, y0 = (int)y0f, z0 = (int)z0f;
    int x1 = x0 + 1, y1 = y0 + 1, z1 = z0 + 1;
    float fx[2] = {1.0f - wx, wx}, fy[2] = {1.0f - wy, wy}, fz[2] = {1.0f - wz, wz};
    float vx[2] = {1.0f, (x1 < 64) ? 1.0f : 0.0f};
    float vy[2] = {1.0f, (y1 < 64) ? 1.0f : 0.0f};
    float vz[2] = {1.0f, (z1 < 64) ? 1.0f : 0.0f};
    int xi[2] = {x0, min(x1, 63)}, yi[2] = {y0, min(y1, 63)}, zi[2] = {z0, min(z1, 63)};
    int o[8]; float w[8];
#pragma unroll
    for (int dz = 0; dz < 2; ++dz)
#pragma unroll
        for (int dy = 0; dy < 2; ++dy)
#pragma unroll
            for (int dx = 0; dx < 2; ++dx) {
                int tt = (dz << 2) | (dy << 1) | dx;
                w[tt] = (((fx[dx] * fy[dy]) * fz[dz]) * vx[dx]) * (vy[dy] * vz[dz]);
                o[tt] = (zi[dz] * 64 + yi[dy]) * 64 + xi[dx];
            }
    float acc = 0.0f;
#pragma unroll 2
    for (int c = 0; c < 16; ++c) {
        const float* ec = e + (size_t)c * 262144;
        const float* gc = g + (size_t)c * 262144;
        float ei = 0.0f, gi = 0.0f;
#pragma unroll
        for (int tt = 0; tt < 8; ++tt) {
            ei = ei + ec[o[tt]] * w[tt];
            gi = gi + gc[o[tt]] * w[tt];
        }
        acc += (gi >= 0.0f) ? ei : 0.0f;
    }
    return acc;
}

__global__ __launch_bounds__(256) void ctri_main_D(
    const float* __restrict__ coords,
    const float* __restrict__ lx,  const float* __restrict__ ly,  const float* __restrict__ lz,
    const float* __restrict__ lxg, const float* __restrict__ lyg, const float* __restrict__ lzg,
    const float* __restrict__ pxy, const float* __restrict__ pyz, const float* __restrict__ pxz,
    const float* __restrict__ pxyg, const float* __restrict__ pyzg, const float* __restrict__ pxzg,
    const float* __restrict__ vol, const float* __restrict__ volg,
    float* __restrict__ out, int P)
{
    float lc = block_line_const(lx, ly, lz, lxg, lyg, lzg);
    int p = blockIdx.x * blockDim.x + threadIdx.x;
    if (p >= P) return;
    float x = coords[3 * p + 0];
    float y = coords[3 * p + 1];
    float z = coords[3 * p + 2];
    float acc = lc;
    acc += sample_plane_pair_D(pxy, pxyg, x, y);
    acc += sample_plane_pair_D(pyz, pyzg, y, z);
    acc += sample_plane_pair_D(pxz, pxzg, x, z);
    acc += sample_volume_D(vol, volg, x, y, z);
    out[p] = acc;
}

// ---------------------------------------------------------------------------
extern "C" void kernel_launch(void* const* d_in, const int* in_sizes, int n_in,
                              void* d_out, int out_size, void* d_ws, size_t ws_size,
                              hipStream_t stream)
{
    (void)n_in; (void)out_size;
    const float* coords = (const float*)d_in[0];
    const float* pxy  = (const float*)d_in[1];
    const float* pyz  = (const float*)d_in[2];
    const float* pxz  = (const float*)d_in[3];
    const float* pxyg = (const float*)d_in[4];
    const float* pyzg = (const float*)d_in[5];
    const float* pxzg = (const float*)d_in[6];
    const float* lx   = (const float*)d_in[7];
    const float* ly   = (const float*)d_in[8];
    const float* lz   = (const float*)d_in[9];
    const float* lxg  = (const float*)d_in[10];
    const float* lyg  = (const float*)d_in[11];
    const float* lzg  = (const float*)d_in[12];
    const float* vol  = (const float*)d_in[13];
    const float* volg = (const float*)d_in[14];
    float* out = (float*)d_out;

    const int P = in_sizes[0] / 3;                        // 262144
    const int pblocks = (P + 255) / 256;                  // 1024
    const size_t planeRec = (size_t)16384 * 192;          // 3 MB each
    const size_t volRec   = (size_t)262144 * 96;          // 24 MB
    const size_t tabBytes = 3 * planeRec + volRec;        // ~34.6 MB
    const size_t permBytes = (size_t)P * 4;               // 1 MB
    const size_t histBytes = (size_t)pblocks * 512 * 4;   // 2 MB
    const size_t need_bytes = tabBytes + permBytes + 2 * histBytes + 512 * 4;

    if (ws_size >= need_bytes) {
        char* tpxy = (char*)d_ws;
        char* tpyz = tpxy + planeRec;
        char* tpxz = tpyz + planeRec;
        char* tv   = tpxz + planeRec;
        u32* perm   = (u32*)(tv + volRec);
        u32* hist   = perm + P;
        u32* base   = hist + (size_t)pblocks * 512;
        u32* totals = base + (size_t)pblocks * 512;

        fused_prep_count<<<2816 + pblocks, 256, 0, stream>>>(
            pxy, pxyg, pyz, pyzg, pxz, pxzg, vol, volg,
            tpxy, tpyz, tpxz, tv, coords, hist, P);
        cell_base<<<512, 256, 0, stream>>>(hist, base, totals, pblocks);
        bucket_scatter2<<<pblocks, 256, 0, stream>>>(coords, base, totals, perm, P);

        const int mblocks = (P * 4 + 255) / 256;          // 4096, multiple of 8
        ctri_main_L<<<mblocks, 256, 0, stream>>>(coords, perm, lx, ly, lz, lxg, lyg, lzg,
                                                 tpxy, tpyz, tpxz, tv, out, P, mblocks);
    } else {
        ctri_main_D<<<pblocks, 256, 0, stream>>>(coords, lx, ly, lz, lxg, lyg, lzg,
                                                 pxy, pyz, pxz, pxyg, pyzg, pxzg,
                                                 vol, volg, out, P);
    }
}

// Round 10
// 191.732 us; speedup vs baseline: 4.8433x; 1.0268x over previous
//
#include <hip/hip_runtime.h>
#include <hip/hip_bf16.h>

#pragma clang fp contract(off)

typedef unsigned short u16;
typedef unsigned int u32;
typedef __attribute__((ext_vector_type(4))) float f32x4;
typedef __attribute__((ext_vector_type(8))) unsigned short u16x8;
typedef __attribute__((ext_vector_type(4))) unsigned short u16x4;

__device__ __forceinline__ float bf2f(u16 u) {
    union { unsigned int i; float f; } v; v.i = ((unsigned int)u) << 16; return v.f;
}
__device__ __forceinline__ u16 f2bf(float f) {
    __hip_bfloat16 h = __float2bfloat16(f);  // RNE
    return *(u16*)&h;
}

__device__ __forceinline__ int cell_of(float x, float y, float z)
{
    int cx = (int)fminf(fmaxf((x + 1.0f) * 4.0f, 0.0f), 7.0f);
    int cy = (int)fminf(fmaxf((y + 1.0f) * 4.0f, 0.0f), 7.0f);
    int cz = (int)fminf(fmaxf((z + 1.0f) * 4.0f, 0.0f), 7.0f);
    return cx + (cy << 3) + (cz << 6);
}

// ---------------------------------------------------------------------------
// Fused prep + histogram kernel.
//   blocks [0,768):    plane record prep (which = b>>8)
//   blocks [768,2816):  volume record prep
//   blocks [2816,3840): per-block 512-cell histogram of coords -> hist
// Record: [ECH x bf16 e | ECH x f32 g]. Phase-2 writes are 16 B per lane:
// a record is RECB/16 segments; both shapes give 768 segments per block.
// ---------------------------------------------------------------------------
__global__ __launch_bounds__(256) void fused_prep_count(
    const float* __restrict__ pxy, const float* __restrict__ pxyg,
    const float* __restrict__ pyz, const float* __restrict__ pyzg,
    const float* __restrict__ pxz, const float* __restrict__ pxzg,
    const float* __restrict__ vol, const float* __restrict__ volg,
    char* __restrict__ tpxy, char* __restrict__ tpyz, char* __restrict__ tpxz,
    char* __restrict__ tv,
    const float* __restrict__ coords, u32* __restrict__ hist, int P)
{
    __shared__ float smem[4160];          // 64*65 floats (>= 32*129)
    const int b = blockIdx.x;
    const int t = threadIdx.x;

    if (b < 768) {
        // ---- plane prep: CC=64, TP=64, ECH=32, RECB=192, stride=65 ----
        int which = b >> 8, blk = b & 255;
        const float* e = (which == 0) ? pxy  : (which == 1) ? pyz  : pxz;
        const float* g = (which == 0) ? pxyg : (which == 1) ? pyzg : pxzg;
        char* dst      = (which == 0) ? tpxy : (which == 1) ? tpyz : tpxz;
        const int tbase = blk * 64;
#pragma unroll
        for (int i = 0; i < 16; ++i) {
            int eidx = i * 256 + t;
            int c  = eidx >> 6;
            int pl = eidx & 63;
            const float* src = (c < 32) ? e : g;
            int cs = (c < 32) ? c : (c - 32);
            smem[c * 65 + pl] = src[(size_t)cs * 16384 + tbase + pl];
        }
        __syncthreads();
#pragma unroll
        for (int i = 0; i < 3; ++i) {          // 768 segments of 16 B
            int sid = i * 256 + t;
            int rec = sid / 12;
            int seg = sid % 12;
            char* outp = dst + (size_t)(tbase + rec) * 192 + seg * 16;
            if (seg < 4) {
                u16x8 pk;
#pragma unroll
                for (int k = 0; k < 8; ++k) pk[k] = f2bf(smem[(seg * 8 + k) * 65 + rec]);
                *(u16x8*)outp = pk;
            } else {
                f32x4 pk;
#pragma unroll
                for (int k = 0; k < 4; ++k) pk[k] = smem[(32 + (seg - 4) * 4 + k) * 65 + rec];
                *(f32x4*)outp = pk;
            }
        }
    } else if (b < 2816) {
        // ---- volume prep: CC=32, TP=128, ECH=16, RECB=96, stride=129 ----
        int blk = b - 768;
        const int tbase = blk * 128;
#pragma unroll
        for (int i = 0; i < 16; ++i) {
            int eidx = i * 256 + t;
            int c  = eidx >> 7;
            int pl = eidx & 127;
            const float* src = (c < 16) ? vol : volg;
            int cs = (c < 16) ? c : (c - 16);
            smem[c * 129 + pl] = src[(size_t)cs * 262144 + tbase + pl];
        }
        __syncthreads();
#pragma unroll
        for (int i = 0; i < 3; ++i) {          // 768 segments of 16 B
            int sid = i * 256 + t;
            int rec = sid / 6;
            int seg = sid % 6;
            char* outp = tv + (size_t)(tbase + rec) * 96 + seg * 16;
            if (seg < 2) {
                u16x8 pk;
#pragma unroll
                for (int k = 0; k < 8; ++k) pk[k] = f2bf(smem[(seg * 8 + k) * 129 + rec]);
                *(u16x8*)outp = pk;
            } else {
                f32x4 pk;
#pragma unroll
                for (int k = 0; k < 4; ++k) pk[k] = smem[(16 + (seg - 2) * 4 + k) * 129 + rec];
                *(f32x4*)outp = pk;
            }
        }
    } else {
        u32* h = (u32*)smem;
        int blk = b - 2816;
        h[t] = 0u; h[t + 256] = 0u;
        __syncthreads();
        int p = blk * 256 + t;
        if (p < P) {
            float x = coords[3 * p + 0];
            float y = coords[3 * p + 1];
            float z = coords[3 * p + 2];
            atomicAdd(&h[cell_of(x, y, z)], 1u);
        }
        __syncthreads();
        u32* hb = hist + (size_t)blk * 512;
        hb[t] = h[t];
        hb[t + 256] = h[t + 256];
    }
}

// ---------------------------------------------------------------------------
// Per-cell exclusive scan across blocks: base[b*512+c] = sum_{b'<b} hist[b'][c]
// (NO cell offset), totals[c] = cell total. One block per cell, nb = 1024.
// ---------------------------------------------------------------------------
__global__ __launch_bounds__(256) void cell_base(
    const u32* __restrict__ hist, u32* __restrict__ base,
    u32* __restrict__ totals, int nb)
{
    int c = blockIdx.x;
    int t = threadIdx.x;
    int b0 = t * 4;
    u32 v[4];
#pragma unroll
    for (int i = 0; i < 4; ++i)
        v[i] = (b0 + i < nb) ? hist[(size_t)(b0 + i) * 512 + c] : 0u;
    u32 lsum = v[0] + v[1] + v[2] + v[3];
    __shared__ u32 ls[256];
    ls[t] = lsum;
    __syncthreads();
#pragma unroll
    for (int off = 1; off < 256; off <<= 1) {
        u32 x = (t >= off) ? ls[t - off] : 0u;
        __syncthreads();
        ls[t] += x;
        __syncthreads();
    }
    u32 acc = ls[t] - lsum;   // exclusive across blocks
#pragma unroll
    for (int i = 0; i < 4; ++i) {
        if (b0 + i < nb) base[(size_t)(b0 + i) * 512 + c] = acc;
        acc += v[i];
    }
    if (t == 255) totals[c] = acc;
}

// ---------------------------------------------------------------------------
// Scatter: per-block local 512-entry exclusive scan of cell totals (LDS),
// intra-block ranks via uncontended LDS atomics, no global returning atomics.
// ---------------------------------------------------------------------------
__global__ __launch_bounds__(256) void bucket_scatter2(
    const float* __restrict__ coords, const u32* __restrict__ base,
    const u32* __restrict__ totals, u32* __restrict__ perm, int P)
{
    __shared__ u32 lh[512];
    __shared__ u32 ts[512];
    __shared__ u32 torig[512];
    int t = threadIdx.x;
    lh[t] = 0u; lh[t + 256] = 0u;
    u32 a0 = totals[t], a1 = totals[t + 256];
    ts[t] = a0; ts[t + 256] = a1;
    torig[t] = a0; torig[t + 256] = a1;
    __syncthreads();
#pragma unroll
    for (int off = 1; off < 512; off <<= 1) {
        u32 x0 = (t >= off) ? ts[t - off] : 0u;
        u32 x1 = (t + 256 >= off) ? ts[t + 256 - off] : 0u;
        __syncthreads();
        ts[t] += x0; ts[t + 256] += x1;
        __syncthreads();
    }
    ts[t]       -= torig[t];        // inclusive -> exclusive
    ts[t + 256] -= torig[t + 256];
    __syncthreads();

    int p = blockIdx.x * 256 + t;
    if (p < P) {
        float x = coords[3 * p + 0];
        float y = coords[3 * p + 1];
        float z = coords[3 * p + 2];
        int cell = cell_of(x, y, z);
        u32 rank = atomicAdd(&lh[cell], 1u);
        u32 pos = ts[cell] + base[(size_t)blockIdx.x * 512 + cell] + rank;
        perm[pos] = (u32)p;
    }
}

// ---------------------------------------------------------------------------
// Lane-split plane sampler: lane sub-index s (0..3) owns channels s*8..s*8+7.
// Record 192 B = [32 bf16 e | 32 f32 g]; g accumulated with exact mul+add in
// reference order (sign-critical); e uses fmaf (bf16-quantized, linear path).
// ---------------------------------------------------------------------------
__device__ __forceinline__ float plane_lane(
    const char* __restrict__ tp, float gx, float gy, int s)
{
    float ix = fminf(fmaxf((gx + 1.0f) * 0.5f * 127.0f, 0.0f), 127.0f);
    float iy = fminf(fmaxf((gy + 1.0f) * 0.5f * 127.0f, 0.0f), 127.0f);
    float x0f = floorf(ix), y0f = floorf(iy);
    float wx = ix - x0f, wy = iy - y0f;
    int x0 = (int)x0f, y0 = (int)y0f;
    int x1 = x0 + 1, y1 = y0 + 1;
    float vx1 = (x1 < 128) ? 1.0f : 0.0f;
    float vy1 = (y1 < 128) ? 1.0f : 0.0f;
    int x1c = min(x1, 127), y1c = min(y1, 127);
    float omwx = 1.0f - wx, omwy = 1.0f - wy;
    float ws4[4];
    ws4[0] = omwx * omwy;
    ws4[1] = (wx * omwy) * vx1;
    ws4[2] = (omwx * wy) * vy1;
    ws4[3] = ((wx * wy) * vx1) * vy1;
    unsigned o[4];
    o[0] = (unsigned)(y0  * 128 + x0 ) * 192u;
    o[1] = (unsigned)(y0  * 128 + x1c) * 192u;
    o[2] = (unsigned)(y1c * 128 + x0 ) * 192u;
    o[3] = (unsigned)(y1c * 128 + x1c) * 192u;

    const int eoff = s * 16;
    const int goff = 64 + s * 32;
    f32x4 ea0 = {0.0f, 0.0f, 0.0f, 0.0f}, ea1 = {0.0f, 0.0f, 0.0f, 0.0f};
    f32x4 ga0 = {0.0f, 0.0f, 0.0f, 0.0f}, ga1 = {0.0f, 0.0f, 0.0f, 0.0f};
#pragma unroll
    for (int t = 0; t < 4; ++t) {
        const char* bp = tp + o[t];
        float w = ws4[t];
        u16x8 ev = *(const u16x8*)(bp + eoff);
        f32x4 g0 = *(const f32x4*)(bp + goff);
        f32x4 g1 = *(const f32x4*)(bp + goff + 16);
#pragma unroll
        for (int j = 0; j < 4; ++j) {
            ga0[j] = ga0[j] + g0[j] * w;
            ga1[j] = ga1[j] + g1[j] * w;
            ea0[j] = fmaf(bf2f(ev[j]), w, ea0[j]);
            ea1[j] = fmaf(bf2f(ev[j + 4]), w, ea1[j]);
        }
    }
    float acc = 0.0f;
#pragma unroll
    for (int j = 0; j < 4; ++j) {
        acc += (ga0[j] >= 0.0f) ? ea0[j] : 0.0f;
        acc += (ga1[j] >= 0.0f) ? ea1[j] : 0.0f;
    }
    return acc;
}

// ---------------------------------------------------------------------------
// Lane-split volume sampler: lane s owns channels s*4..s*4+3.
// Record 96 B = [16 bf16 e | 16 f32 g]; reference tt order (dz major).
// ---------------------------------------------------------------------------
__device__ __forceinline__ float vol_lane(
    const char* __restrict__ tv, float gx, float gy, float gz, int s)
{
    float ix = fminf(fmaxf((gx + 1.0f) * 0.5f * 63.0f, 0.0f), 63.0f);
    float iy = fminf(fmaxf((gy + 1.0f) * 0.5f * 63.0f, 0.0f), 63.0f);
    float iz = fminf(fmaxf((gz + 1.0f) * 0.5f * 63.0f, 0.0f), 63.0f);
    float x0f = floorf(ix), y0f = floorf(iy), z0f = floorf(iz);
    float wx = ix - x0f, wy = iy - y0f, wz = iz - z0f;
    int x0 = (int)x0f, y0 = (int)y0f, z0 = (int)z0f;
    int x1 = x0 + 1, y1 = y0 + 1, z1 = z0 + 1;
    float fx[2] = {1.0f - wx, wx}, fy[2] = {1.0f - wy, wy}, fz[2] = {1.0f - wz, wz};
    float vx[2] = {1.0f, (x1 < 64) ? 1.0f : 0.0f};
    float vy[2] = {1.0f, (y1 < 64) ? 1.0f : 0.0f};
    float vz[2] = {1.0f, (z1 < 64) ? 1.0f : 0.0f};
    int xi[2] = {x0, min(x1, 63)}, yi[2] = {y0, min(y1, 63)}, zi[2] = {z0, min(z1, 63)};

    unsigned off[8];
    float w[8];
#pragma unroll
    for (int dz = 0; dz < 2; ++dz)
#pragma unroll
        for (int dy = 0; dy < 2; ++dy)
#pragma unroll
            for (int dx = 0; dx < 2; ++dx) {
                int tt = (dz << 2) | (dy << 1) | dx;   // reference add order
                w[tt] = (((fx[dx] * fy[dy]) * fz[dz]) * vx[dx]) * (vy[dy] * vz[dz]);
                off[tt] = (unsigned)((zi[dz] * 64 + yi[dy]) * 64 + xi[dx]) * 96u;
            }
    const int eoff = s * 8;
    const int goff = 32 + s * 16;
    f32x4 ea = {0.0f, 0.0f, 0.0f, 0.0f}, ga = {0.0f, 0.0f, 0.0f, 0.0f};
#pragma unroll
    for (int tt = 0; tt < 8; ++tt) {
        const char* bp = tv + off[tt];
        float wt = w[tt];
        u16x4 ev = *(const u16x4*)(bp + eoff);
        f32x4 gv = *(const f32x4*)(bp + goff);
#pragma unroll
        for (int j = 0; j < 4; ++j) {
            ga[j] = ga[j] + gv[j] * wt;
            ea[j] = fmaf(bf2f(ev[j]), wt, ea[j]);
        }
    }
    float acc = 0.0f;
#pragma unroll
    for (int j = 0; j < 4; ++j)
        acc += (ga[j] >= 0.0f) ? ea[j] : 0.0f;
    return acc;
}

// ---------------------------------------------------------------------------
// Line term: constant across points (W=1 -> ix=0 wx=0; gy=0 -> iy=63.5)
// ---------------------------------------------------------------------------
__device__ __forceinline__ float line_pair(const float* __restrict__ e,
                                           const float* __restrict__ g, int c)
{
    float ev = e[c * 128 + 63] * 0.5f + e[c * 128 + 64] * 0.5f;
    float gv = g[c * 128 + 63] * 0.5f + g[c * 128 + 64] * 0.5f;
    return (gv >= 0.0f) ? ev : 0.0f;
}

__device__ __forceinline__ float block_line_const(
    const float* lx, const float* ly, const float* lz,
    const float* lxg, const float* lyg, const float* lzg)
{
    __shared__ float lc_sh;
    int t = threadIdx.x;
    if (t < 64) {
        float part = line_pair(lx, lxg, t) + line_pair(ly, lyg, t) + line_pair(lz, lzg, t);
#pragma unroll
        for (int off = 32; off > 0; off >>= 1) part += __shfl_down(part, off);
        if (t == 0) lc_sh = part;
    }
    __syncthreads();
    return lc_sh;
}

// ---------------------------------------------------------------------------
// Main kernel: 4 lanes per point, bucketed order + XCD-contiguous swizzle.
// ---------------------------------------------------------------------------
__global__ __launch_bounds__(256) void ctri_main_L(
    const float* __restrict__ coords, const u32* __restrict__ perm,
    const float* __restrict__ lx,  const float* __restrict__ ly,  const float* __restrict__ lz,
    const float* __restrict__ lxg, const float* __restrict__ lyg, const float* __restrict__ lzg,
    const char* __restrict__ tpxy, const char* __restrict__ tpyz, const char* __restrict__ tpxz,
    const char* __restrict__ tv,
    float* __restrict__ out, int P, int nblk)
{
    float lc = block_line_const(lx, ly, lz, lxg, lyg, lzg);
    int b = blockIdx.x;
    int cpx = nblk >> 3;                 // nblk multiple of 8
    int swz = (b & 7) * cpx + (b >> 3);  // XCD k <- contiguous perm chunk
    int i = swz * 64 + (threadIdx.x >> 2);
    int s = threadIdx.x & 3;
    if (i >= P) return;
    int p = (int)perm[i];
    float x = coords[3 * p + 0];
    float y = coords[3 * p + 1];
    float z = coords[3 * p + 2];
    float part = 0.0f;
    part += plane_lane(tpxy, x, y, s);
    part += plane_lane(tpyz, y, z, s);
    part += plane_lane(tpxz, x, z, s);
    part += vol_lane(tv, x, y, z, s);
    part += __shfl_xor(part, 1, 64);
    part += __shfl_xor(part, 2, 64);
    if (s == 0) out[p] = lc + part;
}

// ---------------------------------------------------------------------------
// Direct-layout f32 fallback (used only if ws_size too small)
// ---------------------------------------------------------------------------
__device__ __forceinline__ float sample_plane_pair_D(
    const float* __restrict__ e, const float* __restrict__ g, float gx, float gy)
{
    float ix = fminf(fmaxf((gx + 1.0f) * 0.5f * 127.0f, 0.0f), 127.0f);
    float iy = fminf(fmaxf((gy + 1.0f) * 0.5f * 127.0f, 0.0f), 127.0f);
    float x0f = floorf(ix), y0f = floorf(iy);
    float wx = ix - x0f, wy = iy - y0f;
    int x0 = (int)x0f, y0 = (int)y0f;
    int x1 = x0 + 1, y1 = y0 + 1;
    float vx1 = (x1 < 128) ? 1.0f : 0.0f;
    float vy1 = (y1 < 128) ? 1.0f : 0.0f;
    int x1c = min(x1, 127), y1c = min(y1, 127);
    float omwx = 1.0f - wx, omwy = 1.0f - wy;
    float w00 = omwx * omwy;
    float w10 = (wx * omwy) * vx1;
    float w01 = (omwx * wy) * vy1;
    float w11 = ((wx * wy) * vx1) * vy1;
    int o00 = y0 * 128 + x0, o10 = y0 * 128 + x1c;
    int o01 = y1c * 128 + x0, o11 = y1c * 128 + x1c;
    float acc = 0.0f;
#pragma unroll 4
    for (int c = 0; c < 32; ++c) {
        const float* ec = e + (size_t)c * 16384;
        const float* gc = g + (size_t)c * 16384;
        float ei = ((ec[o00] * w00 + ec[o10] * w10) + ec[o01] * w01) + ec[o11] * w11;
        float gi = ((gc[o00] * w00 + gc[o10] * w10) + gc[o01] * w01) + gc[o11] * w11;
        acc += (gi >= 0.0f) ? ei : 0.0f;
    }
    return acc;
}

__device__ __forceinline__ float sample_volume_D(
    const float* __restrict__ e, const float* __restrict__ g,
    float gx, float gy, float gz)
{
    float ix = fminf(fmaxf((gx + 1.0f) * 0.5f * 63.0f, 0.0f), 63.0f);
    float iy = fminf(fmaxf((gy + 1.0f) * 0.5f * 63.0f, 0.0f), 63.0f);
    float iz = fminf(fmaxf((gz + 1.0f) * 0.5f * 63.0f, 0.0f), 63.0f);
    float x0f = floorf(ix), y0f = floorf(iy), z0f = floorf(iz);
    float wx = ix - x0f, wy = iy - y0f, wz = iz - z0f;
    int x0 = (int)x0f, y0 = (int)y0f, z0 = (int)z0f;
    int x1 = x0 + 1, y1 = y0 + 1, z1 = z0 + 1;
    float fx[2] = {1.0f - wx, wx}, fy[2] = {1.0f - wy, wy}, fz[2] = {1.0f - wz, wz};
    float vx[2] = {1.0f, (x1 < 64) ? 1.0f : 0.0f};
    float vy[2] = {1.0f, (y1 < 64) ? 1.0f : 0.0f};
    float vz[2] = {1.0f, (z1 < 64) ? 1.0f : 0.0f};
    int xi[2] = {x0, min(x1, 63)}, yi[2] = {y0, min(y1, 63)}, zi[2] = {z0, min(z1, 63)};
    int o[8]; float w[8];
#pragma unroll
    for (int dz = 0; dz < 2; ++dz)
#pragma unroll
        for (int dy = 0; dy < 2; ++dy)
#pragma unroll
            for (int dx = 0; dx < 2; ++dx) {
                int tt = (dz << 2) | (dy << 1) | dx;
                w[tt] = (((fx[dx] * fy[dy]) * fz[dz]) * vx[dx]) * (vy[dy] * vz[dz]);
                o[tt] = (zi[dz] * 64 + yi[dy]) * 64 + xi[dx];
            }
    float acc = 0.0f;
#pragma unroll 2
    for (int c = 0; c < 16; ++c) {
        const float* ec = e + (size_t)c * 262144;
        const float* gc = g + (size_t)c * 262144;
        float ei = 0.0f, gi = 0.0f;
#pragma unroll
        for (int tt = 0; tt < 8; ++tt) {
            ei = ei + ec[o[tt]] * w[tt];
            gi = gi + gc[o[tt]] * w[tt];
        }
        acc += (gi >= 0.0f) ? ei : 0.0f;
    }
    return acc;
}

__global__ __launch_bounds__(256) void ctri_main_D(
    const float* __restrict__ coords,
    const float* __restrict__ lx,  const float* __restrict__ ly,  const float* __restrict__ lz,
    const float* __restrict__ lxg, const float* __restrict__ lyg, const float* __restrict__ lzg,
    const float* __restrict__ pxy, const float* __restrict__ pyz, const float* __restrict__ pxz,
    const float* __restrict__ pxyg, const float* __restrict__ pyzg, const float* __restrict__ pxzg,
    const float* __restrict__ vol, const float* __restrict__ volg,
    float* __restrict__ out, int P)
{
    float lc = block_line_const(lx, ly, lz, lxg, lyg, lzg);
    int p = blockIdx.x * blockDim.x + threadIdx.x;
    if (p >= P) return;
    float x = coords[3 * p + 0];
    float y = coords[3 * p + 1];
    float z = coords[3 * p + 2];
    float acc = lc;
    acc += sample_plane_pair_D(pxy, pxyg, x, y);
    acc += sample_plane_pair_D(pyz, pyzg, y, z);
    acc += sample_plane_pair_D(pxz, pxzg, x, z);
    acc += sample_volume_D(vol, volg, x, y, z);
    out[p] = acc;
}

// ---------------------------------------------------------------------------
extern "C" void kernel_launch(void* const* d_in, const int* in_sizes, int n_in,
                              void* d_out, int out_size, void* d_ws, size_t ws_size,
                              hipStream_t stream)
{
    (void)n_in; (void)out_size;
    const float* coords = (const float*)d_in[0];
    const float* pxy  = (const float*)d_in[1];
    const float* pyz  = (const float*)d_in[2];
    const float* pxz  = (const float*)d_in[3];
    const float* pxyg = (const float*)d_in[4];
    const float* pyzg = (const float*)d_in[5];
    const float* pxzg = (const float*)d_in[6];
    const float* lx   = (const float*)d_in[7];
    const float* ly   = (const float*)d_in[8];
    const float* lz   = (const float*)d_in[9];
    const float* lxg  = (const float*)d_in[10];
    const float* lyg  = (const float*)d_in[11];
    const float* lzg  = (const float*)d_in[12];
    const float* vol  = (const float*)d_in[13];
    const float* volg = (const float*)d_in[14];
    float* out = (float*)d_out;

    const int P = in_sizes[0] / 3;                        // 262144
    const int pblocks = (P + 255) / 256;                  // 1024
    const size_t planeRec = (size_t)16384 * 192;          // 3 MB each
    const size_t volRec   = (size_t)262144 * 96;          // 24 MB
    const size_t tabBytes = 3 * planeRec + volRec;        // ~34.6 MB
    const size_t permBytes = (size_t)P * 4;               // 1 MB
    const size_t histBytes = (size_t)pblocks * 512 * 4;   // 2 MB
    const size_t need_bytes = tabBytes + permBytes + 2 * histBytes + 512 * 4;

    if (ws_size >= need_bytes) {
        char* tpxy = (char*)d_ws;
        char* tpyz = tpxy + planeRec;
        char* tpxz = tpyz + planeRec;
        char* tv   = tpxz + planeRec;
        u32* perm   = (u32*)(tv + volRec);
        u32* hist   = perm + P;
        u32* base   = hist + (size_t)pblocks * 512;
        u32* totals = base + (size_t)pblocks * 512;

        fused_prep_count<<<2816 + pblocks, 256, 0, stream>>>(
            pxy, pxyg, pyz, pyzg, pxz, pxzg, vol, volg,
            tpxy, tpyz, tpxz, tv, coords, hist, P);
        cell_base<<<512, 256, 0, stream>>>(hist, base, totals, pblocks);
        bucket_scatter2<<<pblocks, 256, 0, stream>>>(coords, base, totals, perm, P);

        const int mblocks = (P * 4 + 255) / 256;          // 4096, multiple of 8
        ctri_main_L<<<mblocks, 256, 0, stream>>>(coords, perm, lx, ly, lz, lxg, lyg, lzg,
                                                 tpxy, tpyz, tpxz, tv, out, P, mblocks);
    } else {
        ctri_main_D<<<pblocks, 256, 0, stream>>>(coords, lx, ly, lz, lxg, lyg, lzg,
                                                 pxy, pyz, pxz, pxyg, pyzg, pxzg,
                                                 vol, volg, out, P);
    }
}

// Round 11
// 185.812 us; speedup vs baseline: 4.9976x; 1.0319x over previous
//
#include <hip/hip_runtime.h>
#include <hip/hip_bf16.h>

#pragma clang fp contract(off)

typedef unsigned short u16;
typedef unsigned int u32;
typedef __attribute__((ext_vector_type(4))) float f32x4;
typedef __attribute__((ext_vector_type(8))) unsigned short u16x8;
typedef __attribute__((ext_vector_type(4))) unsigned short u16x4;

__device__ __forceinline__ float bf2f(u16 u) {
    union { unsigned int i; float f; } v; v.i = ((unsigned int)u) << 16; return v.f;
}
__device__ __forceinline__ u16 f2bf(float f) {
    __hip_bfloat16 h = __float2bfloat16(f);  // RNE
    return *(u16*)&h;
}

__device__ __forceinline__ int cell_of(float x, float y, float z)
{
    int cx = (int)fminf(fmaxf((x + 1.0f) * 4.0f, 0.0f), 7.0f);
    int cy = (int)fminf(fmaxf((y + 1.0f) * 4.0f, 0.0f), 7.0f);
    int cz = (int)fminf(fmaxf((z + 1.0f) * 4.0f, 0.0f), 7.0f);
    return cx + (cy << 3) + (cz << 6);
}

// ---------------------------------------------------------------------------
// Fused prep + histogram kernel.
//   blocks [0,768):    plane record prep (which = b>>8)   stride 68 (f32x4-aligned)
//   blocks [768,2816):  volume record prep                 stride 132
//   blocks [2816,3840): per-block 512-cell histogram of coords -> hist
// Phase-1: float4 global loads (16 B/lane). Phase-2: 16 B/lane stores.
// Record: [ECH x bf16 e | ECH x f32 g].
// ---------------------------------------------------------------------------
__global__ __launch_bounds__(256) void fused_prep_count(
    const float* __restrict__ pxy, const float* __restrict__ pxyg,
    const float* __restrict__ pyz, const float* __restrict__ pyzg,
    const float* __restrict__ pxz, const float* __restrict__ pxzg,
    const float* __restrict__ vol, const float* __restrict__ volg,
    char* __restrict__ tpxy, char* __restrict__ tpyz, char* __restrict__ tpxz,
    char* __restrict__ tv,
    const float* __restrict__ coords, u32* __restrict__ hist, int P)
{
    __shared__ float smem[4352];          // 64*68 floats (>= 32*132)
    const int b = blockIdx.x;
    const int t = threadIdx.x;

    if (b < 768) {
        // ---- plane prep: CC=64, TP=64, ECH=32, RECB=192, stride=68 ----
        int which = b >> 8, blk = b & 255;
        const float* e = (which == 0) ? pxy  : (which == 1) ? pyz  : pxz;
        const float* g = (which == 0) ? pxyg : (which == 1) ? pyzg : pxzg;
        char* dst      = (which == 0) ? tpxy : (which == 1) ? tpyz : tpxz;
        const int tbase = blk * 64;
#pragma unroll
        for (int i = 0; i < 4; ++i) {          // 1024 float4 loads
            int eidx = i * 256 + t;
            int c = eidx >> 4;                  // row (channel slot)
            int q = eidx & 15;                  // float4 within row
            const float* src = (c < 32) ? e : g;
            int cs = (c < 32) ? c : (c - 32);
            f32x4 v = *(const f32x4*)(src + (size_t)cs * 16384 + tbase + q * 4);
            *(f32x4*)&smem[c * 68 + q * 4] = v;
        }
        __syncthreads();
#pragma unroll
        for (int i = 0; i < 3; ++i) {          // 768 segments of 16 B
            int sid = i * 256 + t;
            int rec = sid / 12;
            int seg = sid % 12;
            char* outp = dst + (size_t)(tbase + rec) * 192 + seg * 16;
            if (seg < 4) {
                u16x8 pk;
#pragma unroll
                for (int k = 0; k < 8; ++k) pk[k] = f2bf(smem[(seg * 8 + k) * 68 + rec]);
                *(u16x8*)outp = pk;
            } else {
                f32x4 pk;
#pragma unroll
                for (int k = 0; k < 4; ++k) pk[k] = smem[(32 + (seg - 4) * 4 + k) * 68 + rec];
                *(f32x4*)outp = pk;
            }
        }
    } else if (b < 2816) {
        // ---- volume prep: CC=32, TP=128, ECH=16, RECB=96, stride=132 ----
        int blk = b - 768;
        const int tbase = blk * 128;
#pragma unroll
        for (int i = 0; i < 4; ++i) {          // 1024 float4 loads
            int eidx = i * 256 + t;
            int c = eidx >> 5;
            int q = eidx & 31;
            const float* src = (c < 16) ? vol : volg;
            int cs = (c < 16) ? c : (c - 16);
            f32x4 v = *(const f32x4*)(src + (size_t)cs * 262144 + tbase + q * 4);
            *(f32x4*)&smem[c * 132 + q * 4] = v;
        }
        __syncthreads();
#pragma unroll
        for (int i = 0; i < 3; ++i) {          // 768 segments of 16 B
            int sid = i * 256 + t;
            int rec = sid / 6;
            int seg = sid % 6;
            char* outp = tv + (size_t)(tbase + rec) * 96 + seg * 16;
            if (seg < 2) {
                u16x8 pk;
#pragma unroll
                for (int k = 0; k < 8; ++k) pk[k] = f2bf(smem[(seg * 8 + k) * 132 + rec]);
                *(u16x8*)outp = pk;
            } else {
                f32x4 pk;
#pragma unroll
                for (int k = 0; k < 4; ++k) pk[k] = smem[(16 + (seg - 2) * 4 + k) * 132 + rec];
                *(f32x4*)outp = pk;
            }
        }
    } else {
        u32* h = (u32*)smem;
        int blk = b - 2816;
        h[t] = 0u; h[t + 256] = 0u;
        __syncthreads();
        int p = blk * 256 + t;
        if (p < P) {
            float x = coords[3 * p + 0];
            float y = coords[3 * p + 1];
            float z = coords[3 * p + 2];
            atomicAdd(&h[cell_of(x, y, z)], 1u);
        }
        __syncthreads();
        u32* hb = hist + (size_t)blk * 512;
        hb[t] = h[t];
        hb[t + 256] = h[t + 256];
    }
}

// ---------------------------------------------------------------------------
// Per-cell exclusive scan across blocks: base[b*512+c] = sum_{b'<b} hist[b'][c]
// (NO cell offset), totals[c] = cell total. One block per cell, nb = 1024.
// ---------------------------------------------------------------------------
__global__ __launch_bounds__(256) void cell_base(
    const u32* __restrict__ hist, u32* __restrict__ base,
    u32* __restrict__ totals, int nb)
{
    int c = blockIdx.x;
    int t = threadIdx.x;
    int b0 = t * 4;
    u32 v[4];
#pragma unroll
    for (int i = 0; i < 4; ++i)
        v[i] = (b0 + i < nb) ? hist[(size_t)(b0 + i) * 512 + c] : 0u;
    u32 lsum = v[0] + v[1] + v[2] + v[3];
    __shared__ u32 ls[256];
    ls[t] = lsum;
    __syncthreads();
#pragma unroll
    for (int off = 1; off < 256; off <<= 1) {
        u32 x = (t >= off) ? ls[t - off] : 0u;
        __syncthreads();
        ls[t] += x;
        __syncthreads();
    }
    u32 acc = ls[t] - lsum;   // exclusive across blocks
#pragma unroll
    for (int i = 0; i < 4; ++i) {
        if (b0 + i < nb) base[(size_t)(b0 + i) * 512 + c] = acc;
        acc += v[i];
    }
    if (t == 255) totals[c] = acc;
}

// ---------------------------------------------------------------------------
// Scatter: per-block local 512-entry exclusive scan of cell totals (LDS),
// intra-block ranks via uncontended LDS atomics, no global returning atomics.
// ---------------------------------------------------------------------------
__global__ __launch_bounds__(256) void bucket_scatter2(
    const float* __restrict__ coords, const u32* __restrict__ base,
    const u32* __restrict__ totals, u32* __restrict__ perm, int P)
{
    __shared__ u32 lh[512];
    __shared__ u32 ts[512];
    __shared__ u32 torig[512];
    int t = threadIdx.x;
    lh[t] = 0u; lh[t + 256] = 0u;
    u32 a0 = totals[t], a1 = totals[t + 256];
    ts[t] = a0; ts[t + 256] = a1;
    torig[t] = a0; torig[t + 256] = a1;
    __syncthreads();
#pragma unroll
    for (int off = 1; off < 512; off <<= 1) {
        u32 x0 = (t >= off) ? ts[t - off] : 0u;
        u32 x1 = (t + 256 >= off) ? ts[t + 256 - off] : 0u;
        __syncthreads();
        ts[t] += x0; ts[t + 256] += x1;
        __syncthreads();
    }
    ts[t]       -= torig[t];        // inclusive -> exclusive
    ts[t + 256] -= torig[t + 256];
    __syncthreads();

    int p = blockIdx.x * 256 + t;
    if (p < P) {
        float x = coords[3 * p + 0];
        float y = coords[3 * p + 1];
        float z = coords[3 * p + 2];
        int cell = cell_of(x, y, z);
        u32 rank = atomicAdd(&lh[cell], 1u);
        u32 pos = ts[cell] + base[(size_t)blockIdx.x * 512 + cell] + rank;
        perm[pos] = (u32)p;
    }
}

// ---------------------------------------------------------------------------
// Lane-split plane sampler: lane sub-index s (0..3) owns channels s*8..s*8+7.
// Record 192 B = [32 bf16 e | 32 f32 g]; g accumulated with exact mul+add in
// reference order (sign-critical); e uses fmaf (bf16-quantized, linear path).
// ---------------------------------------------------------------------------
__device__ __forceinline__ float plane_lane(
    const char* __restrict__ tp, float gx, float gy, int s)
{
    float ix = fminf(fmaxf((gx + 1.0f) * 0.5f * 127.0f, 0.0f), 127.0f);
    float iy = fminf(fmaxf((gy + 1.0f) * 0.5f * 127.0f, 0.0f), 127.0f);
    float x0f = floorf(ix), y0f = floorf(iy);
    float wx = ix - x0f, wy = iy - y0f;
    int x0 = (int)x0f, y0 = (int)y0f;
    int x1 = x0 + 1, y1 = y0 + 1;
    float vx1 = (x1 < 128) ? 1.0f : 0.0f;
    float vy1 = (y1 < 128) ? 1.0f : 0.0f;
    int x1c = min(x1, 127), y1c = min(y1, 127);
    float omwx = 1.0f - wx, omwy = 1.0f - wy;
    float ws4[4];
    ws4[0] = omwx * omwy;
    ws4[1] = (wx * omwy) * vx1;
    ws4[2] = (omwx * wy) * vy1;
    ws4[3] = ((wx * wy) * vx1) * vy1;
    unsigned o[4];
    o[0] = (unsigned)(y0  * 128 + x0 ) * 192u;
    o[1] = (unsigned)(y0  * 128 + x1c) * 192u;
    o[2] = (unsigned)(y1c * 128 + x0 ) * 192u;
    o[3] = (unsigned)(y1c * 128 + x1c) * 192u;

    const int eoff = s * 16;
    const int goff = 64 + s * 32;
    f32x4 ea0 = {0.0f, 0.0f, 0.0f, 0.0f}, ea1 = {0.0f, 0.0f, 0.0f, 0.0f};
    f32x4 ga0 = {0.0f, 0.0f, 0.0f, 0.0f}, ga1 = {0.0f, 0.0f, 0.0f, 0.0f};
#pragma unroll
    for (int t = 0; t < 4; ++t) {
        const char* bp = tp + o[t];
        float w = ws4[t];
        u16x8 ev = *(const u16x8*)(bp + eoff);
        f32x4 g0 = *(const f32x4*)(bp + goff);
        f32x4 g1 = *(const f32x4*)(bp + goff + 16);
#pragma unroll
        for (int j = 0; j < 4; ++j) {
            ga0[j] = ga0[j] + g0[j] * w;
            ga1[j] = ga1[j] + g1[j] * w;
            ea0[j] = fmaf(bf2f(ev[j]), w, ea0[j]);
            ea1[j] = fmaf(bf2f(ev[j + 4]), w, ea1[j]);
        }
    }
    float acc = 0.0f;
#pragma unroll
    for (int j = 0; j < 4; ++j) {
        acc += (ga0[j] >= 0.0f) ? ea0[j] : 0.0f;
        acc += (ga1[j] >= 0.0f) ? ea1[j] : 0.0f;
    }
    return acc;
}

// ---------------------------------------------------------------------------
// Lane-split volume sampler: lane s owns channels s*4..s*4+3.
// Record 96 B = [16 bf16 e | 16 f32 g]; reference tt order (dz major).
// ---------------------------------------------------------------------------
__device__ __forceinline__ float vol_lane(
    const char* __restrict__ tv, float gx, float gy, float gz, int s)
{
    float ix = fminf(fmaxf((gx + 1.0f) * 0.5f * 63.0f, 0.0f), 63.0f);
    float iy = fminf(fmaxf((gy + 1.0f) * 0.5f * 63.0f, 0.0f), 63.0f);
    float iz = fminf(fmaxf((gz + 1.0f) * 0.5f * 63.0f, 0.0f), 63.0f);
    float x0f = floorf(ix), y0f = floorf(iy), z0f = floorf(iz);
    float wx = ix - x0f, wy = iy - y0f, wz = iz - z0f;
    int x0 = (int)x0f, y0 = (int)y0f, z0 = (int)z0f;
    int x1 = x0 + 1, y1 = y0 + 1, z1 = z0 + 1;
    float fx[2] = {1.0f - wx, wx}, fy[2] = {1.0f - wy, wy}, fz[2] = {1.0f - wz, wz};
    float vx[2] = {1.0f, (x1 < 64) ? 1.0f : 0.0f};
    float vy[2] = {1.0f, (y1 < 64) ? 1.0f : 0.0f};
    float vz[2] = {1.0f, (z1 < 64) ? 1.0f : 0.0f};
    int xi[2] = {x0, min(x1, 63)}, yi[2] = {y0, min(y1, 63)}, zi[2] = {z0, min(z1, 63)};

    unsigned off[8];
    float w[8];
#pragma unroll
    for (int dz = 0; dz < 2; ++dz)
#pragma unroll
        for (int dy = 0; dy < 2; ++dy)
#pragma unroll
            for (int dx = 0; dx < 2; ++dx) {
                int tt = (dz << 2) | (dy << 1) | dx;   // reference add order
                w[tt] = (((fx[dx] * fy[dy]) * fz[dz]) * vx[dx]) * (vy[dy] * vz[dz]);
                off[tt] = (unsigned)((zi[dz] * 64 + yi[dy]) * 64 + xi[dx]) * 96u;
            }
    const int eoff = s * 8;
    const int goff = 32 + s * 16;
    f32x4 ea = {0.0f, 0.0f, 0.0f, 0.0f}, ga = {0.0f, 0.0f, 0.0f, 0.0f};
#pragma unroll
    for (int tt = 0; tt < 8; ++tt) {
        const char* bp = tv + off[tt];
        float wt = w[tt];
        u16x4 ev = *(const u16x4*)(bp + eoff);
        f32x4 gv = *(const f32x4*)(bp + goff);
#pragma unroll
        for (int j = 0; j < 4; ++j) {
            ga[j] = ga[j] + gv[j] * wt;
            ea[j] = fmaf(bf2f(ev[j]), wt, ea[j]);
        }
    }
    float acc = 0.0f;
#pragma unroll
    for (int j = 0; j < 4; ++j)
        acc += (ga[j] >= 0.0f) ? ea[j] : 0.0f;
    return acc;
}

// ---------------------------------------------------------------------------
// Line term: constant across points (W=1 -> ix=0 wx=0; gy=0 -> iy=63.5)
// ---------------------------------------------------------------------------
__device__ __forceinline__ float line_pair(const float* __restrict__ e,
                                           const float* __restrict__ g, int c)
{
    float ev = e[c * 128 + 63] * 0.5f + e[c * 128 + 64] * 0.5f;
    float gv = g[c * 128 + 63] * 0.5f + g[c * 128 + 64] * 0.5f;
    return (gv >= 0.0f) ? ev : 0.0f;
}

__device__ __forceinline__ float block_line_const(
    const float* lx, const float* ly, const float* lz,
    const float* lxg, const float* lyg, const float* lzg)
{
    __shared__ float lc_sh;
    int t = threadIdx.x;
    if (t < 64) {
        float part = line_pair(lx, lxg, t) + line_pair(ly, lyg, t) + line_pair(lz, lzg, t);
#pragma unroll
        for (int off = 32; off > 0; off >>= 1) part += __shfl_down(part, off);
        if (t == 0) lc_sh = part;
    }
    __syncthreads();
    return lc_sh;
}

// ---------------------------------------------------------------------------
// Main kernel: 4 lanes per point, TWO points per lane group (independent
// gather chains double in-flight loads), bucketed order + XCD swizzle.
// ---------------------------------------------------------------------------
__global__ __launch_bounds__(256) void ctri_main_L2(
    const float* __restrict__ coords, const u32* __restrict__ perm,
    const float* __restrict__ lx,  const float* __restrict__ ly,  const float* __restrict__ lz,
    const float* __restrict__ lxg, const float* __restrict__ lyg, const float* __restrict__ lzg,
    const char* __restrict__ tpxy, const char* __restrict__ tpyz, const char* __restrict__ tpxz,
    const char* __restrict__ tv,
    float* __restrict__ out, int P, int nblk)
{
    float lc = block_line_const(lx, ly, lz, lxg, lyg, lzg);
    int b = blockIdx.x;
    int cpx = nblk >> 3;                 // nblk multiple of 8
    int swz = (b & 7) * cpx + (b >> 3);  // XCD k <- contiguous perm chunk
    int g = threadIdx.x >> 2;            // 0..63
    int s = threadIdx.x & 3;
    int i0 = swz * 128 + g * 2;
    if (i0 >= P) return;
    int i1 = min(i0 + 1, P - 1);
    int p0 = (int)perm[i0];
    int p1 = (int)perm[i1];
    float x0 = coords[3 * p0 + 0], y0 = coords[3 * p0 + 1], z0 = coords[3 * p0 + 2];
    float x1 = coords[3 * p1 + 0], y1 = coords[3 * p1 + 1], z1 = coords[3 * p1 + 2];
    float a0 = 0.0f, a1 = 0.0f;
    a0 += plane_lane(tpxy, x0, y0, s);   a1 += plane_lane(tpxy, x1, y1, s);
    a0 += plane_lane(tpyz, y0, z0, s);   a1 += plane_lane(tpyz, y1, z1, s);
    a0 += plane_lane(tpxz, x0, z0, s);   a1 += plane_lane(tpxz, x1, z1, s);
    a0 += vol_lane(tv, x0, y0, z0, s);   a1 += vol_lane(tv, x1, y1, z1, s);
    a0 += __shfl_xor(a0, 1, 64);
    a0 += __shfl_xor(a0, 2, 64);
    a1 += __shfl_xor(a1, 1, 64);
    a1 += __shfl_xor(a1, 2, 64);
    if (s == 0) {
        out[p0] = lc + a0;
        if (i0 + 1 < P) out[p1] = lc + a1;
    }
}

// ---------------------------------------------------------------------------
// Direct-layout f32 fallback (used only if ws_size too small)
// ---------------------------------------------------------------------------
__device__ __forceinline__ float sample_plane_pair_D(
    const float* __restrict__ e, const float* __restrict__ g, float gx, float gy)
{
    float ix = fminf(fmaxf((gx + 1.0f) * 0.5f * 127.0f, 0.0f), 127.0f);
    float iy = fminf(fmaxf((gy + 1.0f) * 0.5f * 127.0f, 0.0f), 127.0f);
    float x0f = floorf(ix), y0f = floorf(iy);
    float wx = ix - x0f, wy = iy - y0f;
    int x0 = (int)x0f, y0 = (int)y0f;
    int x1 = x0 + 1, y1 = y0 + 1;
    float vx1 = (x1 < 128) ? 1.0f : 0.0f;
    float vy1 = (y1 < 128) ? 1.0f : 0.0f;
    int x1c = min(x1, 127), y1c = min(y1, 127);
    float omwx = 1.0f - wx, omwy = 1.0f - wy;
    float w00 = omwx * omwy;
    float w10 = (wx * omwy) * vx1;
    float w01 = (omwx * wy) * vy1;
    float w11 = ((wx * wy) * vx1) * vy1;
    int o00 = y0 * 128 + x0, o10 = y0 * 128 + x1c;
    int o01 = y1c * 128 + x0, o11 = y1c * 128 + x1c;
    float acc = 0.0f;
#pragma unroll 4
    for (int c = 0; c < 32; ++c) {
        const float* ec = e + (size_t)c * 16384;
        const float* gc = g + (size_t)c * 16384;
        float ei = ((ec[o00] * w00 + ec[o10] * w10) + ec[o01] * w01) + ec[o11] * w11;
        float gi = ((gc[o00] * w00 + gc[o10] * w10) + gc[o01] * w01) + gc[o11] * w11;
        acc += (gi >= 0.0f) ? ei : 0.0f;
    }
    return acc;
}

__device__ __forceinline__ float sample_volume_D(
    const float* __restrict__ e, const float* __restrict__ g,
    float gx, float gy, float gz)
{
    float ix = fminf(fmaxf((gx + 1.0f) * 0.5f * 63.0f, 0.0f), 63.0f);
    float iy = fminf(fmaxf((gy + 1.0f) * 0.5f * 63.0f, 0.0f), 63.0f);
    float iz = fminf(fmaxf((gz + 1.0f) * 0.5f * 63.0f, 0.0f), 63.0f);
    float x0f = floorf(ix), y0f = floorf(iy), z0f = floorf(iz);
    float wx = ix - x0f, wy = iy - y0f, wz = iz - z0f;
    int x0 = (int)x0f, y0 = (int)y0f, z0 = (int)z0f;
    int x1 = x0 + 1, y1 = y0 + 1, z1 = z0 + 1;
    float fx[2] = {1.0f - wx, wx}, fy[2] = {1.0f - wy, wy}, fz[2] = {1.0f - wz, wz};
    float vx[2] = {1.0f, (x1 < 64) ? 1.0f : 0.0f};
    float vy[2] = {1.0f, (y1 < 64) ? 1.0f : 0.0f};
    float vz[2] = {1.0f, (z1 < 64) ? 1.0f : 0.0f};
    int xi[2] = {x0, min(x1, 63)}, yi[2] = {y0, min(y1, 63)}, zi[2] = {z0, min(z1, 63)};
    int o[8]; float w[8];
#pragma unroll
    for (int dz = 0; dz < 2; ++dz)
#pragma unroll
        for (int dy = 0; dy < 2; ++dy)
#pragma unroll
            for (int dx = 0; dx < 2; ++dx) {
                int tt = (dz << 2) | (dy << 1) | dx;
                w[tt] = (((fx[dx] * fy[dy]) * fz[dz]) * vx[dx]) * (vy[dy] * vz[dz]);
                o[tt] = (zi[dz] * 64 + yi[dy]) * 64 + xi[dx];
            }
    float acc = 0.0f;
#pragma unroll 2
    for (int c = 0; c < 16; ++c) {
        const float* ec = e + (size_t)c * 262144;
        const float* gc = g + (size_t)c * 262144;
        float ei = 0.0f, gi = 0.0f;
#pragma unroll
        for (int tt = 0; tt < 8; ++tt) {
            ei = ei + ec[o[tt]] * w[tt];
            gi = gi + gc[o[tt]] * w[tt];
        }
        acc += (gi >= 0.0f) ? ei : 0.0f;
    }
    return acc;
}

__global__ __launch_bounds__(256) void ctri_main_D(
    const float* __restrict__ coords,
    const float* __restrict__ lx,  const float* __restrict__ ly,  const float* __restrict__ lz,
    const float* __restrict__ lxg, const float* __restrict__ lyg, const float* __restrict__ lzg,
    const float* __restrict__ pxy, const float* __restrict__ pyz, const float* __restrict__ pxz,
    const float* __restrict__ pxyg, const float* __restrict__ pyzg, const float* __restrict__ pxzg,
    const float* __restrict__ vol, const float* __restrict__ volg,
    float* __restrict__ out, int P)
{
    float lc = block_line_const(lx, ly, lz, lxg, lyg, lzg);
    int p = blockIdx.x * blockDim.x + threadIdx.x;
    if (p >= P) return;
    float x = coords[3 * p + 0];
    float y = coords[3 * p + 1];
    float z = coords[3 * p + 2];
    float acc = lc;
    acc += sample_plane_pair_D(pxy, pxyg, x, y);
    acc += sample_plane_pair_D(pyz, pyzg, y, z);
    acc += sample_plane_pair_D(pxz, pxzg, x, z);
    acc += sample_volume_D(vol, volg, x, y, z);
    out[p] = acc;
}

// ---------------------------------------------------------------------------
extern "C" void kernel_launch(void* const* d_in, const int* in_sizes, int n_in,
                              void* d_out, int out_size, void* d_ws, size_t ws_size,
                              hipStream_t stream)
{
    (void)n_in; (void)out_size;
    const float* coords = (const float*)d_in[0];
    const float* pxy  = (const float*)d_in[1];
    const float* pyz  = (const float*)d_in[2];
    const float* pxz  = (const float*)d_in[3];
    const float* pxyg = (const float*)d_in[4];
    const float* pyzg = (const float*)d_in[5];
    const float* pxzg = (const float*)d_in[6];
    const float* lx   = (const float*)d_in[7];
    const float* ly   = (const float*)d_in[8];
    const float* lz   = (const float*)d_in[9];
    const float* lxg  = (const float*)d_in[10];
    const float* lyg  = (const float*)d_in[11];
    const float* lzg  = (const float*)d_in[12];
    const float* vol  = (const float*)d_in[13];
    const float* volg = (const float*)d_in[14];
    float* out = (float*)d_out;

    const int P = in_sizes[0] / 3;                        // 262144
    const int pblocks = (P + 255) / 256;                  // 1024
    const size_t planeRec = (size_t)16384 * 192;          // 3 MB each
    const size_t volRec   = (size_t)262144 * 96;          // 24 MB
    const size_t tabBytes = 3 * planeRec + volRec;        // ~34.6 MB
    const size_t permBytes = (size_t)P * 4;               // 1 MB
    const size_t histBytes = (size_t)pblocks * 512 * 4;   // 2 MB
    const size_t need_bytes = tabBytes + permBytes + 2 * histBytes + 512 * 4;

    if (ws_size >= need_bytes) {
        char* tpxy = (char*)d_ws;
        char* tpyz = tpxy + planeRec;
        char* tpxz = tpyz + planeRec;
        char* tv   = tpxz + planeRec;
        u32* perm   = (u32*)(tv + volRec);
        u32* hist   = perm + P;
        u32* base   = hist + (size_t)pblocks * 512;
        u32* totals = base + (size_t)pblocks * 512;

        fused_prep_count<<<2816 + pblocks, 256, 0, stream>>>(
            pxy, pxyg, pyz, pyzg, pxz, pxzg, vol, volg,
            tpxy, tpyz, tpxz, tv, coords, hist, P);
        cell_base<<<512, 256, 0, stream>>>(hist, base, totals, pblocks);
        bucket_scatter2<<<pblocks, 256, 0, stream>>>(coords, base, totals, perm, P);

        const int mblocks = (P * 2 + 255) / 256;          // 2048, multiple of 8
        ctri_main_L2<<<mblocks, 256, 0, stream>>>(coords, perm, lx, ly, lz, lxg, lyg, lzg,
                                                  tpxy, tpyz, tpxz, tv, out, P, mblocks);
    } else {
        ctri_main_D<<<pblocks, 256, 0, stream>>>(coords, lx, ly, lz, lxg, lyg, lzg,
                                                 pxy, pyz, pxz, pxyg, pyzg, pxzg,
                                                 vol, volg, out, P);
    }
}

// Round 12
// 174.804 us; speedup vs baseline: 5.3123x; 1.0630x over previous
//
#include <hip/hip_runtime.h>
#include <hip/hip_bf16.h>

#pragma clang fp contract(off)

typedef unsigned short u16;
typedef unsigned int u32;
typedef __attribute__((ext_vector_type(4))) float f32x4;
typedef __attribute__((ext_vector_type(8))) unsigned short u16x8;
typedef __attribute__((ext_vector_type(4))) unsigned short u16x4;

__device__ __forceinline__ float bf2f(u16 u) {
    union { unsigned int i; float f; } v; v.i = ((unsigned int)u) << 16; return v.f;
}
__device__ __forceinline__ u16 f2bf(float f) {
    __hip_bfloat16 h = __float2bfloat16(f);  // RNE
    return *(u16*)&h;
}

__device__ __forceinline__ int cell_of(float x, float y, float z)
{
    int cx = (int)fminf(fmaxf((x + 1.0f) * 4.0f, 0.0f), 7.0f);
    int cy = (int)fminf(fmaxf((y + 1.0f) * 4.0f, 0.0f), 7.0f);
    int cz = (int)fminf(fmaxf((z + 1.0f) * 4.0f, 0.0f), 7.0f);
    return cx + (cy << 3) + (cz << 6);
}

// ---------------------------------------------------------------------------
// Fused prep + histogram kernel.
//   blocks [0,768):    plane record prep (which = b>>8)   stride 68
//   blocks [768,2816):  volume record prep                 stride 132
//   blocks [2816,3072): per-chunk 512-cell histogram (1024 points/chunk)
// Record: [ECH x bf16 e | ECH x f32 g].
// ---------------------------------------------------------------------------
__global__ __launch_bounds__(256) void fused_prep_count(
    const float* __restrict__ pxy, const float* __restrict__ pxyg,
    const float* __restrict__ pyz, const float* __restrict__ pyzg,
    const float* __restrict__ pxz, const float* __restrict__ pxzg,
    const float* __restrict__ vol, const float* __restrict__ volg,
    char* __restrict__ tpxy, char* __restrict__ tpyz, char* __restrict__ tpxz,
    char* __restrict__ tv,
    const float* __restrict__ coords, u32* __restrict__ hist, int P)
{
    __shared__ float smem[4352];          // 64*68 floats (>= 32*132)
    const int b = blockIdx.x;
    const int t = threadIdx.x;

    if (b < 768) {
        // ---- plane prep: CC=64, TP=64, ECH=32, RECB=192, stride=68 ----
        int which = b >> 8, blk = b & 255;
        const float* e = (which == 0) ? pxy  : (which == 1) ? pyz  : pxz;
        const float* g = (which == 0) ? pxyg : (which == 1) ? pyzg : pxzg;
        char* dst      = (which == 0) ? tpxy : (which == 1) ? tpyz : tpxz;
        const int tbase = blk * 64;
#pragma unroll
        for (int i = 0; i < 4; ++i) {
            int eidx = i * 256 + t;
            int c = eidx >> 4;
            int q = eidx & 15;
            const float* src = (c < 32) ? e : g;
            int cs = (c < 32) ? c : (c - 32);
            f32x4 v = *(const f32x4*)(src + (size_t)cs * 16384 + tbase + q * 4);
            *(f32x4*)&smem[c * 68 + q * 4] = v;
        }
        __syncthreads();
#pragma unroll
        for (int i = 0; i < 3; ++i) {
            int sid = i * 256 + t;
            int rec = sid / 12;
            int seg = sid % 12;
            char* outp = dst + (size_t)(tbase + rec) * 192 + seg * 16;
            if (seg < 4) {
                u16x8 pk;
#pragma unroll
                for (int k = 0; k < 8; ++k) pk[k] = f2bf(smem[(seg * 8 + k) * 68 + rec]);
                *(u16x8*)outp = pk;
            } else {
                f32x4 pk;
#pragma unroll
                for (int k = 0; k < 4; ++k) pk[k] = smem[(32 + (seg - 4) * 4 + k) * 68 + rec];
                *(f32x4*)outp = pk;
            }
        }
    } else if (b < 2816) {
        // ---- volume prep: CC=32, TP=128, ECH=16, RECB=96, stride=132 ----
        int blk = b - 768;
        const int tbase = blk * 128;
#pragma unroll
        for (int i = 0; i < 4; ++i) {
            int eidx = i * 256 + t;
            int c = eidx >> 5;
            int q = eidx & 31;
            const float* src = (c < 16) ? vol : volg;
            int cs = (c < 16) ? c : (c - 16);
            f32x4 v = *(const f32x4*)(src + (size_t)cs * 262144 + tbase + q * 4);
            *(f32x4*)&smem[c * 132 + q * 4] = v;
        }
        __syncthreads();
#pragma unroll
        for (int i = 0; i < 3; ++i) {
            int sid = i * 256 + t;
            int rec = sid / 6;
            int seg = sid % 6;
            char* outp = tv + (size_t)(tbase + rec) * 96 + seg * 16;
            if (seg < 2) {
                u16x8 pk;
#pragma unroll
                for (int k = 0; k < 8; ++k) pk[k] = f2bf(smem[(seg * 8 + k) * 132 + rec]);
                *(u16x8*)outp = pk;
            } else {
                f32x4 pk;
#pragma unroll
                for (int k = 0; k < 4; ++k) pk[k] = smem[(16 + (seg - 2) * 4 + k) * 132 + rec];
                *(f32x4*)outp = pk;
            }
        }
    } else {
        // ---- histogram: 1024 points per chunk ----
        u32* h = (u32*)smem;
        int blk = b - 2816;
        h[t] = 0u; h[t + 256] = 0u;
        __syncthreads();
#pragma unroll
        for (int i = 0; i < 4; ++i) {
            int p = blk * 1024 + i * 256 + t;
            if (p < P) {
                float x = coords[3 * p + 0];
                float y = coords[3 * p + 1];
                float z = coords[3 * p + 2];
                atomicAdd(&h[cell_of(x, y, z)], 1u);
            }
        }
        __syncthreads();
        u32* hb = hist + (size_t)blk * 512;
        hb[t] = h[t];
        hb[t + 256] = h[t + 256];
    }
}

// ---------------------------------------------------------------------------
// Per-cell exclusive scan across chunks (nb=256, one lane per chunk):
// base[b*512+c] = sum_{b'<b} hist[b'][c], totals[c] = cell total.
// Block 0 also computes the line-term constant into lcout[0].
// ---------------------------------------------------------------------------
__global__ __launch_bounds__(256) void cell_base(
    const u32* __restrict__ hist, u32* __restrict__ base,
    u32* __restrict__ totals, float* __restrict__ lcout,
    const float* __restrict__ lx,  const float* __restrict__ ly,  const float* __restrict__ lz,
    const float* __restrict__ lxg, const float* __restrict__ lyg, const float* __restrict__ lzg,
    int nb)
{
    int c = blockIdx.x;
    int t = threadIdx.x;
    u32 v = (t < nb) ? hist[(size_t)t * 512 + c] : 0u;
    __shared__ u32 ls[256];
    ls[t] = v;
    __syncthreads();
#pragma unroll
    for (int off = 1; off < 256; off <<= 1) {
        u32 x = (t >= off) ? ls[t - off] : 0u;
        __syncthreads();
        ls[t] += x;
        __syncthreads();
    }
    if (t < nb) base[(size_t)t * 512 + c] = ls[t] - v;
    if (t == 255) totals[c] = ls[255];

    if (c == 0 && t < 64) {
        float ev, gv, part = 0.0f;
        ev = lx[t * 128 + 63] * 0.5f + lx[t * 128 + 64] * 0.5f;
        gv = lxg[t * 128 + 63] * 0.5f + lxg[t * 128 + 64] * 0.5f;
        part += (gv >= 0.0f) ? ev : 0.0f;
        ev = ly[t * 128 + 63] * 0.5f + ly[t * 128 + 64] * 0.5f;
        gv = lyg[t * 128 + 63] * 0.5f + lyg[t * 128 + 64] * 0.5f;
        part += (gv >= 0.0f) ? ev : 0.0f;
        ev = lz[t * 128 + 63] * 0.5f + lz[t * 128 + 64] * 0.5f;
        gv = lzg[t * 128 + 63] * 0.5f + lzg[t * 128 + 64] * 0.5f;
        part += (gv >= 0.0f) ? ev : 0.0f;
#pragma unroll
        for (int off = 32; off > 0; off >>= 1) part += __shfl_down(part, off);
        if (t == 0) lcout[0] = part;
    }
}

// ---------------------------------------------------------------------------
// Scatter: 256 blocks x 1024 points. Local 512-entry scan of cell totals
// (amortized over 1024 pts), LDS-atomic ranks, writes sorted {x,y,z,bits(p)}.
// ---------------------------------------------------------------------------
__global__ __launch_bounds__(256) void scatter_sorted(
    const float* __restrict__ coords, const u32* __restrict__ base,
    const u32* __restrict__ totals, f32x4* __restrict__ sorted, int P)
{
    __shared__ u32 lh[512];
    __shared__ u32 ts[512];
    __shared__ u32 torig[512];
    int t = threadIdx.x;
    lh[t] = 0u; lh[t + 256] = 0u;
    u32 a0 = totals[t], a1 = totals[t + 256];
    ts[t] = a0; ts[t + 256] = a1;
    torig[t] = a0; torig[t + 256] = a1;
    __syncthreads();
#pragma unroll
    for (int off = 1; off < 512; off <<= 1) {
        u32 x0 = (t >= off) ? ts[t - off] : 0u;
        u32 x1 = (t + 256 >= off) ? ts[t + 256 - off] : 0u;
        __syncthreads();
        ts[t] += x0; ts[t + 256] += x1;
        __syncthreads();
    }
    ts[t]       -= torig[t];        // inclusive -> exclusive
    ts[t + 256] -= torig[t + 256];
    __syncthreads();

    int blk = blockIdx.x;
#pragma unroll
    for (int i = 0; i < 4; ++i) {
        int p = blk * 1024 + i * 256 + t;
        if (p < P) {
            float x = coords[3 * p + 0];
            float y = coords[3 * p + 1];
            float z = coords[3 * p + 2];
            int cell = cell_of(x, y, z);
            u32 rank = atomicAdd(&lh[cell], 1u);
            u32 pos = ts[cell] + base[(size_t)blk * 512 + cell] + rank;
            f32x4 v = {x, y, z, __uint_as_float((u32)p)};
            sorted[pos] = v;
        }
    }
}

// ---------------------------------------------------------------------------
// Lane-split plane sampler: lane sub-index s (0..3) owns channels s*8..s*8+7.
// Record 192 B = [32 bf16 e | 32 f32 g]; g accumulated with exact mul+add in
// reference order (sign-critical); e uses fmaf (bf16-quantized, linear path).
// ---------------------------------------------------------------------------
__device__ __forceinline__ float plane_lane(
    const char* __restrict__ tp, float gx, float gy, int s)
{
    float ix = fminf(fmaxf((gx + 1.0f) * 0.5f * 127.0f, 0.0f), 127.0f);
    float iy = fminf(fmaxf((gy + 1.0f) * 0.5f * 127.0f, 0.0f), 127.0f);
    float x0f = floorf(ix), y0f = floorf(iy);
    float wx = ix - x0f, wy = iy - y0f;
    int x0 = (int)x0f, y0 = (int)y0f;
    int x1 = x0 + 1, y1 = y0 + 1;
    float vx1 = (x1 < 128) ? 1.0f : 0.0f;
    float vy1 = (y1 < 128) ? 1.0f : 0.0f;
    int x1c = min(x1, 127), y1c = min(y1, 127);
    float omwx = 1.0f - wx, omwy = 1.0f - wy;
    float ws4[4];
    ws4[0] = omwx * omwy;
    ws4[1] = (wx * omwy) * vx1;
    ws4[2] = (omwx * wy) * vy1;
    ws4[3] = ((wx * wy) * vx1) * vy1;
    unsigned o[4];
    o[0] = (unsigned)(y0  * 128 + x0 ) * 192u;
    o[1] = (unsigned)(y0  * 128 + x1c) * 192u;
    o[2] = (unsigned)(y1c * 128 + x0 ) * 192u;
    o[3] = (unsigned)(y1c * 128 + x1c) * 192u;

    const int eoff = s * 16;
    const int goff = 64 + s * 32;
    f32x4 ea0 = {0.0f, 0.0f, 0.0f, 0.0f}, ea1 = {0.0f, 0.0f, 0.0f, 0.0f};
    f32x4 ga0 = {0.0f, 0.0f, 0.0f, 0.0f}, ga1 = {0.0f, 0.0f, 0.0f, 0.0f};
#pragma unroll
    for (int t = 0; t < 4; ++t) {
        const char* bp = tp + o[t];
        float w = ws4[t];
        u16x8 ev = *(const u16x8*)(bp + eoff);
        f32x4 g0 = *(const f32x4*)(bp + goff);
        f32x4 g1 = *(const f32x4*)(bp + goff + 16);
#pragma unroll
        for (int j = 0; j < 4; ++j) {
            ga0[j] = ga0[j] + g0[j] * w;
            ga1[j] = ga1[j] + g1[j] * w;
            ea0[j] = fmaf(bf2f(ev[j]), w, ea0[j]);
            ea1[j] = fmaf(bf2f(ev[j + 4]), w, ea1[j]);
        }
    }
    float acc = 0.0f;
#pragma unroll
    for (int j = 0; j < 4; ++j) {
        acc += (ga0[j] >= 0.0f) ? ea0[j] : 0.0f;
        acc += (ga1[j] >= 0.0f) ? ea1[j] : 0.0f;
    }
    return acc;
}

// ---------------------------------------------------------------------------
// Lane-split volume sampler: lane s owns channels s*4..s*4+3.
// Record 96 B = [16 bf16 e | 16 f32 g]; reference tt order (dz major).
// ---------------------------------------------------------------------------
__device__ __forceinline__ float vol_lane(
    const char* __restrict__ tv, float gx, float gy, float gz, int s)
{
    float ix = fminf(fmaxf((gx + 1.0f) * 0.5f * 63.0f, 0.0f), 63.0f);
    float iy = fminf(fmaxf((gy + 1.0f) * 0.5f * 63.0f, 0.0f), 63.0f);
    float iz = fminf(fmaxf((gz + 1.0f) * 0.5f * 63.0f, 0.0f), 63.0f);
    float x0f = floorf(ix), y0f = floorf(iy), z0f = floorf(iz);
    float wx = ix - x0f, wy = iy - y0f, wz = iz - z0f;
    int x0 = (int)x0f, y0 = (int)y0f, z0 = (int)z0f;
    int x1 = x0 + 1, y1 = y0 + 1, z1 = z0 + 1;
    float fx[2] = {1.0f - wx, wx}, fy[2] = {1.0f - wy, wy}, fz[2] = {1.0f - wz, wz};
    float vx[2] = {1.0f, (x1 < 64) ? 1.0f : 0.0f};
    float vy[2] = {1.0f, (y1 < 64) ? 1.0f : 0.0f};
    float vz[2] = {1.0f, (z1 < 64) ? 1.0f : 0.0f};
    int xi[2] = {x0, min(x1, 63)}, yi[2] = {y0, min(y1, 63)}, zi[2] = {z0, min(z1, 63)};

    unsigned off[8];
    float w[8];
#pragma unroll
    for (int dz = 0; dz < 2; ++dz)
#pragma unroll
        for (int dy = 0; dy < 2; ++dy)
#pragma unroll
            for (int dx = 0; dx < 2; ++dx) {
                int tt = (dz << 2) | (dy << 1) | dx;   // reference add order
                w[tt] = (((fx[dx] * fy[dy]) * fz[dz]) * vx[dx]) * (vy[dy] * vz[dz]);
                off[tt] = (unsigned)((zi[dz] * 64 + yi[dy]) * 64 + xi[dx]) * 96u;
            }
    const int eoff = s * 8;
    const int goff = 32 + s * 16;
    f32x4 ea = {0.0f, 0.0f, 0.0f, 0.0f}, ga = {0.0f, 0.0f, 0.0f, 0.0f};
#pragma unroll
    for (int tt = 0; tt < 8; ++tt) {
        const char* bp = tv + off[tt];
        float wt = w[tt];
        u16x4 ev = *(const u16x4*)(bp + eoff);
        f32x4 gv = *(const f32x4*)(bp + goff);
#pragma unroll
        for (int j = 0; j < 4; ++j) {
            ga[j] = ga[j] + gv[j] * wt;
            ea[j] = fmaf(bf2f(ev[j]), wt, ea[j]);
        }
    }
    float acc = 0.0f;
#pragma unroll
    for (int j = 0; j < 4; ++j)
        acc += (ga[j] >= 0.0f) ? ea[j] : 0.0f;
    return acc;
}

// ---------------------------------------------------------------------------
// Main kernel: 4 lanes/point, 2 points per lane group, sorted float4 input.
// ---------------------------------------------------------------------------
__global__ __launch_bounds__(256) void ctri_main_S2(
    const f32x4* __restrict__ sorted, const float* __restrict__ lcbuf,
    const char* __restrict__ tpxy, const char* __restrict__ tpyz, const char* __restrict__ tpxz,
    const char* __restrict__ tv,
    float* __restrict__ out, int P, int nblk)
{
    float lc = lcbuf[0];
    int b = blockIdx.x;
    int cpx = nblk >> 3;                 // nblk multiple of 8
    int swz = (b & 7) * cpx + (b >> 3);  // XCD k <- contiguous sorted chunk
    int g = threadIdx.x >> 2;            // 0..63
    int s = threadIdx.x & 3;
    int i0 = swz * 128 + g * 2;
    if (i0 >= P) return;
    int i1 = min(i0 + 1, P - 1);
    f32x4 s0 = sorted[i0];
    f32x4 s1 = sorted[i1];
    int p0 = (int)__float_as_uint(s0[3]);
    int p1 = (int)__float_as_uint(s1[3]);
    float a0 = 0.0f, a1 = 0.0f;
    a0 += plane_lane(tpxy, s0[0], s0[1], s);    a1 += plane_lane(tpxy, s1[0], s1[1], s);
    a0 += plane_lane(tpyz, s0[1], s0[2], s);    a1 += plane_lane(tpyz, s1[1], s1[2], s);
    a0 += plane_lane(tpxz, s0[0], s0[2], s);    a1 += plane_lane(tpxz, s1[0], s1[2], s);
    a0 += vol_lane(tv, s0[0], s0[1], s0[2], s); a1 += vol_lane(tv, s1[0], s1[1], s1[2], s);
    a0 += __shfl_xor(a0, 1, 64);
    a0 += __shfl_xor(a0, 2, 64);
    a1 += __shfl_xor(a1, 1, 64);
    a1 += __shfl_xor(a1, 2, 64);
    if (s == 0) {
        out[p0] = lc + a0;
        if (i0 + 1 < P) out[p1] = lc + a1;
    }
}

// ---------------------------------------------------------------------------
// Direct-layout f32 fallback (used only if ws_size too small)
// ---------------------------------------------------------------------------
__device__ __forceinline__ float line_pair(const float* __restrict__ e,
                                           const float* __restrict__ g, int c)
{
    float ev = e[c * 128 + 63] * 0.5f + e[c * 128 + 64] * 0.5f;
    float gv = g[c * 128 + 63] * 0.5f + g[c * 128 + 64] * 0.5f;
    return (gv >= 0.0f) ? ev : 0.0f;
}

__device__ __forceinline__ float block_line_const(
    const float* lx, const float* ly, const float* lz,
    const float* lxg, const float* lyg, const float* lzg)
{
    __shared__ float lc_sh;
    int t = threadIdx.x;
    if (t < 64) {
        float part = line_pair(lx, lxg, t) + line_pair(ly, lyg, t) + line_pair(lz, lzg, t);
#pragma unroll
        for (int off = 32; off > 0; off >>= 1) part += __shfl_down(part, off);
        if (t == 0) lc_sh = part;
    }
    __syncthreads();
    return lc_sh;
}

__device__ __forceinline__ float sample_plane_pair_D(
    const float* __restrict__ e, const float* __restrict__ g, float gx, float gy)
{
    float ix = fminf(fmaxf((gx + 1.0f) * 0.5f * 127.0f, 0.0f), 127.0f);
    float iy = fminf(fmaxf((gy + 1.0f) * 0.5f * 127.0f, 0.0f), 127.0f);
    float x0f = floorf(ix), y0f = floorf(iy);
    float wx = ix - x0f, wy = iy - y0f;
    int x0 = (int)x0f, y0 = (int)y0f;
    int x1 = x0 + 1, y1 = y0 + 1;
    float vx1 = (x1 < 128) ? 1.0f : 0.0f;
    float vy1 = (y1 < 128) ? 1.0f : 0.0f;
    int x1c = min(x1, 127), y1c = min(y1, 127);
    float omwx = 1.0f - wx, omwy = 1.0f - wy;
    float w00 = omwx * omwy;
    float w10 = (wx * omwy) * vx1;
    float w01 = (omwx * wy) * vy1;
    float w11 = ((wx * wy) * vx1) * vy1;
    int o00 = y0 * 128 + x0, o10 = y0 * 128 + x1c;
    int o01 = y1c * 128 + x0, o11 = y1c * 128 + x1c;
    float acc = 0.0f;
#pragma unroll 4
    for (int c = 0; c < 32; ++c) {
        const float* ec = e + (size_t)c * 16384;
        const float* gc = g + (size_t)c * 16384;
        float ei = ((ec[o00] * w00 + ec[o10] * w10) + ec[o01] * w01) + ec[o11] * w11;
        float gi = ((gc[o00] * w00 + gc[o10] * w10) + gc[o01] * w01) + gc[o11] * w11;
        acc += (gi >= 0.0f) ? ei : 0.0f;
    }
    return acc;
}

__device__ __forceinline__ float sample_volume_D(
    const float* __restrict__ e, const float* __restrict__ g,
    float gx, float gy, float gz)
{
    float ix = fminf(fmaxf((gx + 1.0f) * 0.5f * 63.0f, 0.0f), 63.0f);
    float iy = fminf(fmaxf((gy + 1.0f) * 0.5f * 63.0f, 0.0f), 63.0f);
    float iz = fminf(fmaxf((gz + 1.0f) * 0.5f * 63.0f, 0.0f), 63.0f);
    float x0f = floorf(ix), y0f = floorf(iy), z0f = floorf(iz);
    float wx = ix - x0f, wy = iy - y0f, wz = iz - z0f;
    int x0 = (int)x0f, y0 = (int)y0f, z0 = (int)z0f;
    int x1 = x0 + 1, y1 = y0 + 1, z1 = z0 + 1;
    float fx[2] = {1.0f - wx, wx}, fy[2] = {1.0f - wy, wy}, fz[2] = {1.0f - wz, wz};
    float vx[2] = {1.0f, (x1 < 64) ? 1.0f : 0.0f};
    float vy[2] = {1.0f, (y1 < 64) ? 1.0f : 0.0f};
    float vz[2] = {1.0f, (z1 < 64) ? 1.0f : 0.0f};
    int xi[2] = {x0, min(x1, 63)}, yi[2] = {y0, min(y1, 63)}, zi[2] = {z0, min(z1, 63)};
    int o[8]; float w[8];
#pragma unroll
    for (int dz = 0; dz < 2; ++dz)
#pragma unroll
        for (int dy = 0; dy < 2; ++dy)
#pragma unroll
            for (int dx = 0; dx < 2; ++dx) {
                int tt = (dz << 2) | (dy << 1) | dx;
                w[tt] = (((fx[dx] * fy[dy]) * fz[dz]) * vx[dx]) * (vy[dy] * vz[dz]);
                o[tt] = (zi[dz] * 64 + yi[dy]) * 64 + xi[dx];
            }
    float acc = 0.0f;
#pragma unroll 2
    for (int c = 0; c < 16; ++c) {
        const float* ec = e + (size_t)c * 262144;
        const float* gc = g + (size_t)c * 262144;
        float ei = 0.0f, gi = 0.0f;
#pragma unroll
        for (int tt = 0; tt < 8; ++tt) {
            ei = ei + ec[o[tt]] * w[tt];
            gi = gi + gc[o[tt]] * w[tt];
        }
        acc += (gi >= 0.0f) ? ei : 0.0f;
    }
    return acc;
}

__global__ __launch_bounds__(256) void ctri_main_D(
    const float* __restrict__ coords,
    const float* __restrict__ lx,  const float* __restrict__ ly,  const float* __restrict__ lz,
    const float* __restrict__ lxg, const float* __restrict__ lyg, const float* __restrict__ lzg,
    const float* __restrict__ pxy, const float* __restrict__ pyz, const float* __restrict__ pxz,
    const float* __restrict__ pxyg, const float* __restrict__ pyzg, const float* __restrict__ pxzg,
    const float* __restrict__ vol, const float* __restrict__ volg,
    float* __restrict__ out, int P)
{
    float lc = block_line_const(lx, ly, lz, lxg, lyg, lzg);
    int p = blockIdx.x * blockDim.x + threadIdx.x;
    if (p >= P) return;
    float x = coords[3 * p + 0];
    float y = coords[3 * p + 1];
    float z = coords[3 * p + 2];
    float acc = lc;
    acc += sample_plane_pair_D(pxy, pxyg, x, y);
    acc += sample_plane_pair_D(pyz, pyzg, y, z);
    acc += sample_plane_pair_D(pxz, pxzg, x, z);
    acc += sample_volume_D(vol, volg, x, y, z);
    out[p] = acc;
}

// ---------------------------------------------------------------------------
extern "C" void kernel_launch(void* const* d_in, const int* in_sizes, int n_in,
                              void* d_out, int out_size, void* d_ws, size_t ws_size,
                              hipStream_t stream)
{
    (void)n_in; (void)out_size;
    const float* coords = (const float*)d_in[0];
    const float* pxy  = (const float*)d_in[1];
    const float* pyz  = (const float*)d_in[2];
    const float* pxz  = (const float*)d_in[3];
    const float* pxyg = (const float*)d_in[4];
    const float* pyzg = (const float*)d_in[5];
    const float* pxzg = (const float*)d_in[6];
    const float* lx   = (const float*)d_in[7];
    const float* ly   = (const float*)d_in[8];
    const float* lz   = (const float*)d_in[9];
    const float* lxg  = (const float*)d_in[10];
    const float* lyg  = (const float*)d_in[11];
    const float* lzg  = (const float*)d_in[12];
    const float* vol  = (const float*)d_in[13];
    const float* volg = (const float*)d_in[14];
    float* out = (float*)d_out;

    const int P = in_sizes[0] / 3;                        // 262144
    const int chunks = (P + 1023) / 1024;                 // 256
    const size_t planeRec = (size_t)16384 * 192;          // 3 MB each
    const size_t volRec   = (size_t)262144 * 96;          // 24 MB
    const size_t tabBytes = 3 * planeRec + volRec;        // ~34.6 MB
    const size_t sortBytes = (size_t)P * 16;              // 4 MB
    const size_t histBytes = (size_t)chunks * 512 * 4;    // 512 KB
    const size_t need_bytes = tabBytes + sortBytes + 2 * histBytes + 512 * 4 + 64;

    if (ws_size >= need_bytes) {
        char* tpxy = (char*)d_ws;
        char* tpyz = tpxy + planeRec;
        char* tpxz = tpyz + planeRec;
        char* tv   = tpxz + planeRec;
        f32x4* sorted = (f32x4*)(tv + volRec);
        u32* hist   = (u32*)(sorted + P);
        u32* base   = hist + (size_t)chunks * 512;
        u32* totals = base + (size_t)chunks * 512;
        float* lcbuf = (float*)(totals + 512);

        fused_prep_count<<<2816 + chunks, 256, 0, stream>>>(
            pxy, pxyg, pyz, pyzg, pxz, pxzg, vol, volg,
            tpxy, tpyz, tpxz, tv, coords, hist, P);
        cell_base<<<512, 256, 0, stream>>>(hist, base, totals, lcbuf,
                                           lx, ly, lz, lxg, lyg, lzg, chunks);
        scatter_sorted<<<chunks, 256, 0, stream>>>(coords, base, totals, sorted, P);

        const int mblocks = (P * 2 + 255) / 256;          // 2048, multiple of 8
        ctri_main_S2<<<mblocks, 256, 0, stream>>>(sorted, lcbuf,
                                                  tpxy, tpyz, tpxz, tv, out, P, mblocks);
    } else {
        const int pblocks = (P + 255) / 256;
        ctri_main_D<<<pblocks, 256, 0, stream>>>(coords, lx, ly, lz, lxg, lyg, lzg,
                                                 pxy, pyz, pxz, pxyg, pyzg, pxzg,
                                                 vol, volg, out, P);
    }
}